// Round 1
// baseline (372.720 us; speedup 1.0000x reference)
//
#include <hip/hip_runtime.h>
#include <hip/hip_bf16.h>
#include <stdint.h>

// Problem constants: B=4, N=2048, C=1024, H=16, HD=64; 8192 token rows.
typedef __bf16 bf16_t;
typedef __attribute__((ext_vector_type(8))) __bf16 bf16x8;
typedef __attribute__((ext_vector_type(4))) __bf16 bf16x4;
typedef __attribute__((ext_vector_type(4))) float floatx4;

// async global->LDS, 16B per lane; LDS dest is wave-uniform base + lane*16
#define GLDS16(g, l)                                                          \
  __builtin_amdgcn_global_load_lds(                                           \
      (const __attribute__((address_space(1))) void*)(g),                     \
      (__attribute__((address_space(3))) void*)(l), 16, 0, 0)

// ---------------------------------------------------------------------------
// C[M,N] = A[M,K] @ B[N,K]^T (+ bias[N]); A,B bf16 row-major, acc fp32.
// m97 structure: 128x128 tile, BK=32, 4 waves (2x2), 4x4 MFMA tiles/wave,
// global_load_lds width16 staging, 2-barrier K-loop.
// MFMA 16x16x32_bf16 layouts (m89-verified):
//   A-frag: lane holds A[m=lane&15][k=quad*8+j]
//   B-frag: lane holds B[k=quad*8+j][n=lane&15]  (= W row n, contiguous k)
//   C/D:    reg r -> C[row=quad*4+r][col=lane&15]
// ---------------------------------------------------------------------------
template <typename OT, bool ADD>
__global__ __launch_bounds__(256) void gemm_bt(
    const bf16_t* __restrict__ A, const bf16_t* __restrict__ B,
    const float* __restrict__ bias, OT* __restrict__ C, int M, int N, int K) {
  __shared__ bf16_t As[128 * 32];
  __shared__ bf16_t Bs[128 * 32];
  const int tid = threadIdx.x;
  const int wave = tid >> 6;
  const int lane = tid & 63;
  const int quad = lane >> 4;
  const int l16 = lane & 15;
  const int m0 = blockIdx.x * 128;
  const int n0 = blockIdx.y * 128;
  const int wm = (wave >> 1) * 64;
  const int wn = (wave & 1) * 64;

  // staging: chunk c (0..511) = 16B; row=c>>2, byte-off=(c&3)*16.
  // issue q: chunk = q*256 + tid  -> lands at LDS byte chunk*16 (identity).
  const int r0 = tid >> 2;        // row for q=0 (q=1 adds 64)
  const int kc = (tid & 3) * 8;   // element offset in row

  floatx4 acc[4][4];
  const floatx4 zf = {0.f, 0.f, 0.f, 0.f};
#pragma unroll
  for (int i = 0; i < 4; ++i)
#pragma unroll
    for (int j = 0; j < 4; ++j) acc[i][j] = zf;

  const bf16_t* Ab = A + (size_t)(m0 + r0) * K + kc;
  const bf16_t* Bb = B + (size_t)(n0 + r0) * K + kc;
  const size_t rowStep = (size_t)64 * K;
  bf16_t* lA0 = As + (wave * 64) * 8;          // wave-uniform LDS bases
  bf16_t* lA1 = As + (256 + wave * 64) * 8;
  bf16_t* lB0 = Bs + (wave * 64) * 8;
  bf16_t* lB1 = Bs + (256 + wave * 64) * 8;

  for (int k0 = 0; k0 < K; k0 += 32) {
    GLDS16(Ab + k0, lA0);
    GLDS16(Ab + rowStep + k0, lA1);
    GLDS16(Bb + k0, lB0);
    GLDS16(Bb + rowStep + k0, lB1);
    __syncthreads();  // drains vmcnt(0): staged data visible
    bf16x8 af[4], bfr[4];
#pragma unroll
    for (int i = 0; i < 4; ++i)
      af[i] = *(const bf16x8*)(As + (wm + i * 16 + l16) * 32 + quad * 8);
#pragma unroll
    for (int j = 0; j < 4; ++j)
      bfr[j] = *(const bf16x8*)(Bs + (wn + j * 16 + l16) * 32 + quad * 8);
#pragma unroll
    for (int i = 0; i < 4; ++i)
#pragma unroll
      for (int j = 0; j < 4; ++j)
        acc[i][j] = __builtin_amdgcn_mfma_f32_16x16x32_bf16(af[i], bfr[j],
                                                            acc[i][j], 0, 0, 0);
    __syncthreads();  // all waves done reading LDS before next stage
  }

#pragma unroll
  for (int j = 0; j < 4; ++j) {
    const int col = n0 + wn + j * 16 + l16;
    const float bv = bias ? bias[col] : 0.0f;
#pragma unroll
    for (int i = 0; i < 4; ++i) {
      const int rbase = m0 + wm + i * 16 + quad * 4;
#pragma unroll
      for (int r = 0; r < 4; ++r) {
        float v = acc[i][j][r] + bv;
        size_t idx = (size_t)(rbase + r) * N + col;
        if constexpr (ADD)
          C[idx] += v;
        else
          C[idx] = (OT)v;
      }
    }
  }
}

// ---------------------------------------------------------------------------
// fp32 -> bf16 flat convert, 4 elems/thread
// ---------------------------------------------------------------------------
__global__ __launch_bounds__(256) void cvt_k(const float* __restrict__ in,
                                             bf16_t* __restrict__ out, int n4) {
  int i = blockIdx.x * 256 + threadIdx.x;
  if (i >= n4) return;
  floatx4 v = ((const floatx4*)in)[i];
  bf16x4 o;
  o[0] = (bf16_t)v[0];
  o[1] = (bf16_t)v[1];
  o[2] = (bf16_t)v[2];
  o[3] = (bf16_t)v[3];
  ((bf16x4*)out)[i] = o;
}

// W_cp (1024x1024 fp32) -> W_cp^T (1024x1024 bf16), tiled transpose
__global__ __launch_bounds__(256) void transpose_cvt_k(
    const float* __restrict__ in, bf16_t* __restrict__ out) {
  __shared__ float t[32][33];
  const int bx = blockIdx.x * 32, by = blockIdx.y * 32;
  const int tx = threadIdx.x, ty = threadIdx.y;
#pragma unroll
  for (int i = 0; i < 32; i += 8)
    t[ty + i][tx] = in[(size_t)(by + ty + i) * 1024 + bx + tx];
  __syncthreads();
#pragma unroll
  for (int i = 0; i < 32; i += 8)
    out[(size_t)(bx + ty + i) * 1024 + by + tx] = (bf16_t)t[tx][ty + i];
}

// b_comb = W_pw @ b_cp + b_pw  (fp32, one wave per output)
__global__ __launch_bounds__(64) void bcomb_k(const float* __restrict__ Wpw,
                                              const float* __restrict__ bcp,
                                              const float* __restrict__ bpw,
                                              float* __restrict__ outb) {
  const int i = blockIdx.x;
  const int l = threadIdx.x;
  const float* row = Wpw + (size_t)i * 1024;
  float s = 0.f;
  for (int j = l; j < 1024; j += 64) s += row[j] * bcp[j];
#pragma unroll
  for (int o = 32; o > 0; o >>= 1) s += __shfl_down(s, o);
  if (l == 0) outb[i] = s + bpw[i];
}

// ---------------------------------------------------------------------------
// Attention-over-heads: per token row, Q,K,V are 16x64; scores 16x16,
// softmax over g, out = P@V. One wave per token, fp32 internal.
// LDS per wave: q/k/v as fp32, layout (h*3+role)*68 + d (68 keeps float4
// alignment; bank stride 12 -> worst 2-way = free).
// ---------------------------------------------------------------------------
__global__ __launch_bounds__(256) void attn_k(const bf16_t* __restrict__ qkv,
                                              const float* __restrict__ pos,
                                              bf16_t* __restrict__ outp) {
  __shared__ float sh[4 * 3264 + 4 * 272];
  const int tid = threadIdx.x;
  const int wave = tid >> 6, lane = tid & 63;
  const int p = blockIdx.x * 4 + wave;  // token row 0..8191
  float* shw = sh + wave * 3264;
  float* pl = sh + 4 * 3264 + wave * 272;

  // stage 3072 bf16 -> fp32 LDS (channel c: h=c/192, role=(c%192)/64, d=c%64)
  const uint32_t* src = (const uint32_t*)(qkv + (size_t)p * 3072);
  for (int i = 0; i < 24; ++i) {
    uint32_t w = src[lane + i * 64];
    int c = 2 * (lane + i * 64);
    int h = c / 192;
    int rem = c - h * 192;
    int role = rem >> 6, d = rem & 63;
    float* dst = shw + (h * 3 + role) * 68 + d;
    dst[0] = __uint_as_float(w << 16);
    dst[1] = __uint_as_float(w & 0xffff0000u);
  }
  __syncthreads();

  // scores: lane -> h = lane&15, g in {quad*4 .. quad*4+3}
  const int l16 = lane & 15, quad = lane >> 4;
  const int h = l16, g0 = quad * 4;
  const float* qrow = shw + h * 204;               // role 0
  const float* krow = shw + (g0 * 3 + 1) * 68;     // role 1, +204 per g
  const floatx4 zf = {0.f, 0.f, 0.f, 0.f};
  floatx4 s4[4] = {zf, zf, zf, zf};
  for (int d = 0; d < 64; d += 4) {
    floatx4 qv = *(const floatx4*)(qrow + d);
    s4[0] += qv * *(const floatx4*)(krow + d);
    s4[1] += qv * *(const floatx4*)(krow + 204 + d);
    s4[2] += qv * *(const floatx4*)(krow + 408 + d);
    s4[3] += qv * *(const floatx4*)(krow + 612 + d);
  }
  const float* pb = pos + (size_t)(p & 2047) * 256 + h * 16 + g0;
  float s[4];
#pragma unroll
  for (int jj = 0; jj < 4; ++jj)
    s[jj] = (s4[jj][0] + s4[jj][1] + s4[jj][2] + s4[jj][3]) * 0.125f + pb[jj];

  // softmax over g: row h lives in lanes {h, h+16, h+32, h+48}
  float m = fmaxf(fmaxf(s[0], s[1]), fmaxf(s[2], s[3]));
  m = fmaxf(m, __shfl_xor(m, 16));
  m = fmaxf(m, __shfl_xor(m, 32));
  float e[4], sum = 0.f;
#pragma unroll
  for (int jj = 0; jj < 4; ++jj) {
    e[jj] = __expf(s[jj] - m);
    sum += e[jj];
  }
  sum += __shfl_xor(sum, 16);
  sum += __shfl_xor(sum, 32);
  const float inv = 1.0f / sum;
#pragma unroll
  for (int jj = 0; jj < 4; ++jj) pl[h * 17 + g0 + jj] = e[jj] * inv;
  __syncthreads();

  // out[h2][d] = sum_g p[h2][g] * v[g][d]; lane -> h2=lane>>2, d-chunk of 16
  const int h2 = lane >> 2, dbase = (lane & 3) * 16;
  floatx4 o0 = zf, o1 = zf, o2 = zf, o3 = zf;
  for (int g = 0; g < 16; ++g) {
    float pw = pl[h2 * 17 + g];
    const float* vr = shw + g * 204 + 136 + dbase;  // role 2
    o0 += pw * *(const floatx4*)(vr);
    o1 += pw * *(const floatx4*)(vr + 4);
    o2 += pw * *(const floatx4*)(vr + 8);
    o3 += pw * *(const floatx4*)(vr + 12);
  }
  union {
    bf16_t b[16];
    uint4 u4[2];
  } pk;
#pragma unroll
  for (int t2 = 0; t2 < 4; ++t2) {
    pk.b[t2] = (bf16_t)o0[t2];
    pk.b[4 + t2] = (bf16_t)o1[t2];
    pk.b[8 + t2] = (bf16_t)o2[t2];
    pk.b[12 + t2] = (bf16_t)o3[t2];
  }
  uint4* dst = (uint4*)(outp + (size_t)p * 1024 + h2 * 64 + dbase);
  dst[0] = pk.u4[0];
  dst[1] = pk.u4[1];
}

// depthwise conv k=3 over seq (pad=1, per batch), bf16 in/out
__global__ __launch_bounds__(256) void dwconv_k(const bf16_t* __restrict__ in,
                                                const float* __restrict__ Wdw,
                                                const float* __restrict__ bdw,
                                                bf16_t* __restrict__ out) {
  const int idx = blockIdx.x * 256 + threadIdx.x;  // 0..8388607
  const int c = idx & 1023;
  const int n = (idx >> 10) & 2047;
  const float w0 = Wdw[c * 3], w1 = Wdw[c * 3 + 1], w2 = Wdw[c * 3 + 2];
  float a = bdw[c];
  float xm = (n > 0) ? (float)in[idx - 1024] : 0.f;
  float xc = (float)in[idx];
  float xp = (n < 2047) ? (float)in[idx + 1024] : 0.f;
  out[idx] = (bf16_t)(a + xm * w0 + xc * w1 + xp * w2);
}

// ---------------------------------------------------------------------------
extern "C" void kernel_launch(void* const* d_in, const int* in_sizes, int n_in,
                              void* d_out, int out_size, void* d_ws,
                              size_t ws_size, hipStream_t stream) {
  (void)in_sizes;
  (void)n_in;
  (void)out_size;
  (void)ws_size;
  const float* x = (const float*)d_in[0];
  const float* Wqkv = (const float*)d_in[1];
  const float* bqkv = (const float*)d_in[2];
  const float* Wout = (const float*)d_in[3];
  const float* bout = (const float*)d_in[4];
  const float* pos = (const float*)d_in[5];
  const float* Wcp = (const float*)d_in[6];
  const float* bcp = (const float*)d_in[7];
  const float* Wpw = (const float*)d_in[8];
  const float* bpw = (const float*)d_in[9];
  const float* Wdw = (const float*)d_in[10];
  const float* bdw = (const float*)d_in[11];
  const float* Wtw = (const float*)d_in[12];
  const float* btw = (const float*)d_in[13];
  float* out = (float*)d_out;

  char* ws = (char*)d_ws;
  size_t off = 0;
  auto alloc = [&](size_t bytes) -> void* {
    void* pp = ws + off;
    off += (bytes + 255) & ~(size_t)255;
    return pp;
  };
  bf16_t* x_bf = (bf16_t*)alloc(8388608ull * 2);
  bf16_t* Wqkv_bf = (bf16_t*)alloc(3145728ull * 2);
  bf16_t* Wout_bf = (bf16_t*)alloc(1048576ull * 2);
  bf16_t* Wpw_bf = (bf16_t*)alloc(1048576ull * 2);
  bf16_t* WcpT_bf = (bf16_t*)alloc(1048576ull * 2);
  bf16_t* Wtw_bf = (bf16_t*)alloc(1048576ull * 2);
  bf16_t* Wcomb_bf = (bf16_t*)alloc(1048576ull * 2);
  float* bcomb = (float*)alloc(1024 * 4);
  bf16_t* qkv_bf = (bf16_t*)alloc(25165824ull * 2);  // 8192 x 3072
  bf16_t* attn_bf = (bf16_t*)alloc(8388608ull * 2);
  // conv intermediates reuse the qkv region (dead after out_proj)
  bf16_t* xc2 = qkv_bf;
  bf16_t* xc3 = qkv_bf + 12582912;

  // fp32 -> bf16 conversions
  cvt_k<<<8192, 256, 0, stream>>>(x, x_bf, 2097152);
  cvt_k<<<3072, 256, 0, stream>>>(Wqkv, Wqkv_bf, 786432);
  cvt_k<<<1024, 256, 0, stream>>>(Wout, Wout_bf, 262144);
  cvt_k<<<1024, 256, 0, stream>>>(Wpw, Wpw_bf, 262144);
  cvt_k<<<1024, 256, 0, stream>>>(Wtw, Wtw_bf, 262144);
  transpose_cvt_k<<<dim3(32, 32), dim3(32, 8), 0, stream>>>(Wcp, WcpT_bf);
  bcomb_k<<<1024, 64, 0, stream>>>(Wpw, bcp, bpw, bcomb);

  // W_comb = W_pw @ W_cp  (as bf16 gemm over W_cp^T rows)
  gemm_bt<bf16_t, false><<<dim3(8, 8), 256, 0, stream>>>(
      Wpw_bf, WcpT_bf, nullptr, Wcomb_bf, 1024, 1024, 1024);

  // attention branch
  gemm_bt<bf16_t, false><<<dim3(64, 24), 256, 0, stream>>>(
      x_bf, Wqkv_bf, bqkv, qkv_bf, 8192, 3072, 1024);
  attn_k<<<2048, 256, 0, stream>>>(qkv_bf, pos, attn_bf);
  gemm_bt<float, false><<<dim3(64, 8), 256, 0, stream>>>(
      attn_bf, Wout_bf, bout, out, 8192, 1024, 1024);

  // conv branch (fused cp+pw via W_comb)
  gemm_bt<bf16_t, false><<<dim3(64, 8), 256, 0, stream>>>(
      x_bf, Wcomb_bf, bcomb, xc2, 8192, 1024, 1024);
  dwconv_k<<<32768, 256, 0, stream>>>(xc2, Wdw, bdw, xc3);
  gemm_bt<float, true><<<dim3(64, 8), 256, 0, stream>>>(xc3, Wtw_bf, btw, out,
                                                        8192, 1024, 1024);
}

// Round 2
// 350.062 us; speedup vs baseline: 1.0647x; 1.0647x over previous
//
#include <hip/hip_runtime.h>
#include <hip/hip_bf16.h>
#include <stdint.h>

// B=4, N=2048, C=1024, H=16, HD=64; 8192 token rows.
typedef __bf16 bf16_t;
typedef __attribute__((ext_vector_type(8))) __bf16 bf16x8;
typedef __attribute__((ext_vector_type(4))) __bf16 bf16x4;
typedef __attribute__((ext_vector_type(4))) float floatx4;

#define GLDS16(g, l)                                                          \
  __builtin_amdgcn_global_load_lds(                                           \
      (const __attribute__((address_space(1))) void*)(g),                     \
      (__attribute__((address_space(3))) void*)(l), 16, 0, 0)

// ---------------------------------------------------------------------------
// C[M,N] = A[M,K] @ B[N,K]^T (+ bias[N]); bf16 in, fp32 acc.
// 128x128 tile, BK=32, 4 waves 2x2, 4x4 MFMA tiles/wave, glds w16 staging.
// LDS swizzle: row R's 16B k-chunk q stored at granule 4R + ((q - sR)&3),
// sR = (R + R>>2)&3. Staging fetches swizzled source chunk (coalescing
// unchanged: 4 lanes still cover one 64B row segment, permuted). Fragment
// read offset ((quad + sR)&3)*8 is lane-constant. Bank phases over a
// 16-lane group hit all 8 phases exactly 2x -> conflict-free (m136: 2-way
// is free).
// ---------------------------------------------------------------------------
template <typename OT>
__global__ __launch_bounds__(256) void gemm_bt(
    const bf16_t* __restrict__ A, const bf16_t* __restrict__ B,
    const float* __restrict__ bias, OT* __restrict__ C, int M, int N, int K) {
  __shared__ bf16_t As[128 * 32];
  __shared__ bf16_t Bs[128 * 32];
  const int tid = threadIdx.x;
  const int wave = tid >> 6;
  const int lane = tid & 63;
  const int quad = lane >> 4;
  const int l16 = lane & 15;
  const int m0 = blockIdx.x * 128;
  const int n0 = blockIdx.y * 128;
  const int wm = (wave >> 1) * 64;
  const int wn = (wave & 1) * 64;

  // staging: lane covers granule (issue*256 + tid); row r0 (+64 for issue 1),
  // source k-chunk swizzled by sR (invariant under +64).
  const int r0 = tid >> 2;
  const int sw = (r0 + (r0 >> 2)) & 3;
  const int kc = (((tid & 3) - sw) & 3) * 8;

  // fragment read offset: chunk quad of row (wm+i*16+l16) is at position
  // ((quad + sR)&3), sR = (l16 + (l16>>2))&3 (wm, i*16 drop out mod 4).
  const int koff = ((quad + l16 + (l16 >> 2)) & 3) * 8;

  floatx4 acc[4][4];
  const floatx4 zf = {0.f, 0.f, 0.f, 0.f};
#pragma unroll
  for (int i = 0; i < 4; ++i)
#pragma unroll
    for (int j = 0; j < 4; ++j) acc[i][j] = zf;

  const bf16_t* Ab = A + (size_t)(m0 + r0) * K + kc;
  const bf16_t* Bb = B + (size_t)(n0 + r0) * K + kc;
  const size_t rowStep = (size_t)64 * K;
  bf16_t* lA0 = As + (wave * 64) * 8;
  bf16_t* lA1 = As + (256 + wave * 64) * 8;
  bf16_t* lB0 = Bs + (wave * 64) * 8;
  bf16_t* lB1 = Bs + (256 + wave * 64) * 8;

  for (int k0 = 0; k0 < K; k0 += 32) {
    GLDS16(Ab + k0, lA0);
    GLDS16(Ab + rowStep + k0, lA1);
    GLDS16(Bb + k0, lB0);
    GLDS16(Bb + rowStep + k0, lB1);
    __syncthreads();
    bf16x8 af[4], bfr[4];
#pragma unroll
    for (int i = 0; i < 4; ++i)
      af[i] = *(const bf16x8*)(As + (wm + i * 16 + l16) * 32 + koff);
#pragma unroll
    for (int j = 0; j < 4; ++j)
      bfr[j] = *(const bf16x8*)(Bs + (wn + j * 16 + l16) * 32 + koff);
#pragma unroll
    for (int i = 0; i < 4; ++i)
#pragma unroll
      for (int j = 0; j < 4; ++j)
        acc[i][j] = __builtin_amdgcn_mfma_f32_16x16x32_bf16(af[i], bfr[j],
                                                            acc[i][j], 0, 0, 0);
    __syncthreads();
  }

#pragma unroll
  for (int j = 0; j < 4; ++j) {
    const int col = n0 + wn + j * 16 + l16;
    const float bv = bias ? bias[col] : 0.0f;
#pragma unroll
    for (int i = 0; i < 4; ++i) {
      const int rbase = m0 + wm + i * 16 + quad * 4;
#pragma unroll
      for (int r = 0; r < 4; ++r) {
        float v = acc[i][j][r] + bv;
        C[(size_t)(rbase + r) * N + col] = (OT)v;
      }
    }
  }
}

// fp32 -> bf16 flat convert, 4 elems/thread
__global__ __launch_bounds__(256) void cvt_k(const float* __restrict__ in,
                                             bf16_t* __restrict__ out, int n4) {
  int i = blockIdx.x * 256 + threadIdx.x;
  if (i >= n4) return;
  floatx4 v = ((const floatx4*)in)[i];
  bf16x4 o;
  o[0] = (bf16_t)v[0];
  o[1] = (bf16_t)v[1];
  o[2] = (bf16_t)v[2];
  o[3] = (bf16_t)v[3];
  ((bf16x4*)out)[i] = o;
}

// fp32 (1024x1024) -> bf16 rows placed at stride 2048 (for K-concat weights)
__global__ __launch_bounds__(256) void cvt_strided_k(
    const float* __restrict__ in, bf16_t* __restrict__ out) {
  int i = blockIdx.x * 256 + threadIdx.x;  // 262144 chunks of 4
  floatx4 v = ((const floatx4*)in)[i];
  bf16x4 o;
  o[0] = (bf16_t)v[0];
  o[1] = (bf16_t)v[1];
  o[2] = (bf16_t)v[2];
  o[3] = (bf16_t)v[3];
  int row = i >> 8, c4 = i & 255;
  *(bf16x4*)(out + (size_t)row * 2048 + c4 * 4) = o;
}

// W_cp (1024x1024 fp32) -> W_cp^T bf16
__global__ __launch_bounds__(256) void transpose_cvt_k(
    const float* __restrict__ in, bf16_t* __restrict__ out) {
  __shared__ float t[32][33];
  const int bx = blockIdx.x * 32, by = blockIdx.y * 32;
  const int tx = threadIdx.x, ty = threadIdx.y;
#pragma unroll
  for (int i = 0; i < 32; i += 8)
    t[ty + i][tx] = in[(size_t)(by + ty + i) * 1024 + bx + tx];
  __syncthreads();
#pragma unroll
  for (int i = 0; i < 32; i += 8)
    out[(size_t)(bx + ty + i) * 1024 + by + tx] = (bf16_t)t[tx][ty + i];
}

// b_comb = W_pw @ b_cp + b_pw
__global__ __launch_bounds__(64) void bcomb_k(const float* __restrict__ Wpw,
                                              const float* __restrict__ bcp,
                                              const float* __restrict__ bpw,
                                              float* __restrict__ outb) {
  const int i = blockIdx.x;
  const int l = threadIdx.x;
  const float* row = Wpw + (size_t)i * 1024;
  float s = 0.f;
  for (int j = l; j < 1024; j += 64) s += row[j] * bcp[j];
#pragma unroll
  for (int o = 32; o > 0; o >>= 1) s += __shfl_down(s, o);
  if (l == 0) outb[i] = s + bpw[i];
}

// bias2 = bout + btw
__global__ __launch_bounds__(256) void bsum_k(const float* __restrict__ a,
                                              const float* __restrict__ b,
                                              float* __restrict__ o) {
  int i = blockIdx.x * 256 + threadIdx.x;
  o[i] = a[i] + b[i];
}

// ---------------------------------------------------------------------------
// Attention-over-heads: per token, Q,K,V 16x64, scores 16x16, softmax, P@V.
// One wave per token. qstride/ostride parameterize the packed buffers.
// ---------------------------------------------------------------------------
__global__ __launch_bounds__(256) void attn_k(const bf16_t* __restrict__ qkv,
                                              const float* __restrict__ pos,
                                              bf16_t* __restrict__ outp,
                                              int qstride, int ostride) {
  __shared__ float sh[4 * 3264 + 4 * 272];
  const int tid = threadIdx.x;
  const int wave = tid >> 6, lane = tid & 63;
  const int p = blockIdx.x * 4 + wave;
  float* shw = sh + wave * 3264;
  float* pl = sh + 4 * 3264 + wave * 272;

  const uint32_t* src = (const uint32_t*)(qkv + (size_t)p * qstride);
  for (int i = 0; i < 24; ++i) {
    uint32_t w = src[lane + i * 64];
    int c = 2 * (lane + i * 64);
    int h = c / 192;
    int rem = c - h * 192;
    int role = rem >> 6, d = rem & 63;
    float* dst = shw + (h * 3 + role) * 68 + d;
    dst[0] = __uint_as_float(w << 16);
    dst[1] = __uint_as_float(w & 0xffff0000u);
  }
  __syncthreads();

  const int l16 = lane & 15, quad = lane >> 4;
  const int h = l16, g0 = quad * 4;
  const float* qrow = shw + h * 204;
  const float* krow = shw + (g0 * 3 + 1) * 68;
  const floatx4 zf = {0.f, 0.f, 0.f, 0.f};
  floatx4 s4[4] = {zf, zf, zf, zf};
  for (int d = 0; d < 64; d += 4) {
    floatx4 qv = *(const floatx4*)(qrow + d);
    s4[0] += qv * *(const floatx4*)(krow + d);
    s4[1] += qv * *(const floatx4*)(krow + 204 + d);
    s4[2] += qv * *(const floatx4*)(krow + 408 + d);
    s4[3] += qv * *(const floatx4*)(krow + 612 + d);
  }
  const float* pb = pos + (size_t)(p & 2047) * 256 + h * 16 + g0;
  float s[4];
#pragma unroll
  for (int jj = 0; jj < 4; ++jj)
    s[jj] = (s4[jj][0] + s4[jj][1] + s4[jj][2] + s4[jj][3]) * 0.125f + pb[jj];

  float m = fmaxf(fmaxf(s[0], s[1]), fmaxf(s[2], s[3]));
  m = fmaxf(m, __shfl_xor(m, 16));
  m = fmaxf(m, __shfl_xor(m, 32));
  float e[4], sum = 0.f;
#pragma unroll
  for (int jj = 0; jj < 4; ++jj) {
    e[jj] = __expf(s[jj] - m);
    sum += e[jj];
  }
  sum += __shfl_xor(sum, 16);
  sum += __shfl_xor(sum, 32);
  const float inv = 1.0f / sum;
#pragma unroll
  for (int jj = 0; jj < 4; ++jj) pl[h * 17 + g0 + jj] = e[jj] * inv;
  __syncthreads();

  const int h2 = lane >> 2, dbase = (lane & 3) * 16;
  floatx4 o0 = zf, o1 = zf, o2 = zf, o3 = zf;
  for (int g = 0; g < 16; ++g) {
    float pw = pl[h2 * 17 + g];
    const float* vr = shw + g * 204 + 136 + dbase;
    o0 += pw * *(const floatx4*)(vr);
    o1 += pw * *(const floatx4*)(vr + 4);
    o2 += pw * *(const floatx4*)(vr + 8);
    o3 += pw * *(const floatx4*)(vr + 12);
  }
  union {
    bf16_t b[16];
    uint4 u4[2];
  } pk;
#pragma unroll
  for (int t2 = 0; t2 < 4; ++t2) {
    pk.b[t2] = (bf16_t)o0[t2];
    pk.b[4 + t2] = (bf16_t)o1[t2];
    pk.b[8 + t2] = (bf16_t)o2[t2];
    pk.b[12 + t2] = (bf16_t)o3[t2];
  }
  uint4* dst = (uint4*)(outp + (size_t)p * ostride + h2 * 64 + dbase);
  dst[0] = pk.u4[0];
  dst[1] = pk.u4[1];
}

// depthwise conv k=3 over seq; in row-stride 4096 (already offset to conv
// cols), out row-stride 2048 (already offset to second K-half).
__global__ __launch_bounds__(256) void dwconv_k(const bf16_t* __restrict__ in,
                                                const float* __restrict__ Wdw,
                                                const float* __restrict__ bdw,
                                                bf16_t* __restrict__ out) {
  const int idx = blockIdx.x * 256 + threadIdx.x;  // 8192*1024
  const int c = idx & 1023;
  const int t = idx >> 10;
  const int n = t & 2047;
  const bf16_t* ip = in + (size_t)t * 4096 + c;
  const float w0 = Wdw[c * 3], w1 = Wdw[c * 3 + 1], w2 = Wdw[c * 3 + 2];
  float xm = (n > 0) ? (float)ip[-4096] : 0.f;
  float xc = (float)ip[0];
  float xp = (n < 2047) ? (float)ip[4096] : 0.f;
  out[(size_t)t * 2048 + c] = (bf16_t)(bdw[c] + xm * w0 + xc * w1 + xp * w2);
}

// ---------------------------------------------------------------------------
extern "C" void kernel_launch(void* const* d_in, const int* in_sizes, int n_in,
                              void* d_out, int out_size, void* d_ws,
                              size_t ws_size, hipStream_t stream) {
  (void)in_sizes; (void)n_in; (void)out_size; (void)ws_size;
  const float* x = (const float*)d_in[0];
  const float* Wqkv = (const float*)d_in[1];
  const float* bqkv = (const float*)d_in[2];
  const float* Wout = (const float*)d_in[3];
  const float* bout = (const float*)d_in[4];
  const float* pos = (const float*)d_in[5];
  const float* Wcp = (const float*)d_in[6];
  const float* bcp = (const float*)d_in[7];
  const float* Wpw = (const float*)d_in[8];
  const float* bpw = (const float*)d_in[9];
  const float* Wdw = (const float*)d_in[10];
  const float* bdw = (const float*)d_in[11];
  const float* Wtw = (const float*)d_in[12];
  const float* btw = (const float*)d_in[13];
  float* out = (float*)d_out;

  char* ws = (char*)d_ws;
  const size_t MB = 1024ull * 1024ull;
  // Overlay A [0, 32MB): pre-GEMM1 buffers, later reused as Mid.
  bf16_t* x_bf = (bf16_t*)(ws + 0);              // 16 MB
  bf16_t* Wbig1 = (bf16_t*)(ws + 16 * MB);       // 8 MB: [Wqkv ; Wcomb]
  bf16_t* WcpT = (bf16_t*)(ws + 24 * MB);        // 2 MB
  bf16_t* Wpw_bf = (bf16_t*)(ws + 26 * MB);      // 2 MB
  bf16_t* Mid = (bf16_t*)(ws + 0);               // 32 MB (after GEMM1)
  // Persistent
  bf16_t* Wbig2 = (bf16_t*)(ws + 32 * MB);       // 4 MB: [Wout|Wtw] K-concat
  float* bias1 = (float*)(ws + 36 * MB);         // 16 KB
  float* bias2 = (float*)(ws + 36 * MB + 65536); // 4 KB
  bf16_t* G1out = (bf16_t*)(ws + 37 * MB);       // 64 MB: 8192 x 4096

  // conversions / weight prep
  cvt_k<<<8192, 256, 0, stream>>>(x, x_bf, 2097152);
  cvt_k<<<3072, 256, 0, stream>>>(Wqkv, Wbig1, 786432);
  transpose_cvt_k<<<dim3(32, 32), dim3(32, 8), 0, stream>>>(Wcp, WcpT);
  cvt_k<<<1024, 256, 0, stream>>>(Wpw, Wpw_bf, 262144);
  cvt_strided_k<<<1024, 256, 0, stream>>>(Wout, Wbig2);
  cvt_strided_k<<<1024, 256, 0, stream>>>(Wtw, Wbig2 + 1024);
  bcomb_k<<<1024, 64, 0, stream>>>(Wpw, bcp, bpw, bias1 + 3072);
  hipMemcpyAsync(bias1, bqkv, 3072 * sizeof(float), hipMemcpyDeviceToDevice,
                 stream);
  bsum_k<<<4, 256, 0, stream>>>(bout, btw, bias2);

  // W_comb = W_pw @ W_cp -> rows 3072..4095 of Wbig1
  gemm_bt<bf16_t><<<dim3(8, 8), 256, 0, stream>>>(
      Wpw_bf, WcpT, nullptr, Wbig1 + (size_t)3072 * 1024, 1024, 1024, 1024);

  // GEMM1: x @ [Wqkv ; Wcomb]^T + [bqkv ; bcomb] -> 8192 x 4096
  gemm_bt<bf16_t><<<dim3(64, 32), 256, 0, stream>>>(
      x_bf, Wbig1, bias1, G1out, 8192, 4096, 1024);

  // attention (cols 0..3071) -> Mid cols 0..1023
  attn_k<<<2048, 256, 0, stream>>>(G1out, pos, Mid, 4096, 2048);
  // depthwise conv on cols 3072..4095 -> Mid cols 1024..2047
  dwconv_k<<<32768, 256, 0, stream>>>(G1out + 3072, Wdw, bdw, Mid + 1024);

  // GEMM2: [attn|dwc] @ [Wout|Wtw]^T + (bout+btw) -> out (fp32)
  gemm_bt<float><<<dim3(64, 8), 256, 0, stream>>>(Mid, Wbig2, bias2, out,
                                                  8192, 1024, 2048);
}

// Round 3
// 309.575 us; speedup vs baseline: 1.2040x; 1.1308x over previous
//
#include <hip/hip_runtime.h>
#include <hip/hip_bf16.h>
#include <stdint.h>

// B=4, N=2048, C=1024, H=16, HD=64; 8192 token rows.
typedef __bf16 bf16_t;
typedef __attribute__((ext_vector_type(8))) __bf16 bf16x8;
typedef __attribute__((ext_vector_type(4))) __bf16 bf16x4;
typedef __attribute__((ext_vector_type(4))) float floatx4;

#define GLDS16(g, l)                                                          \
  __builtin_amdgcn_global_load_lds(                                           \
      (const __attribute__((address_space(1))) void*)(g),                     \
      (__attribute__((address_space(3))) void*)(l), 16, 0, 0)

// ---------------------------------------------------------------------------
// C[M,N] = A[M,K] @ B[N,K]^T (+ bias[N]); bf16 in, fp32 acc.
// 128x128 tile, BK=64 (32 KB LDS), 4 waves 2x2, 4x4 MFMA tiles/wave.
// Staging: 16B granule at LDS position p of row R holds source granule
// p ^ (R&7) (XOR swizzle; GLDS identity lane map + 128B/row coalescing kept).
// Fragment read for k-step ks: position (ks*4+quad) ^ (l16&7) — lane-const.
// Operand swap: mfma(Bfrag, Afrag, acc) -> lane reg r holds
// C[m0+wm+i*16+l16][n0+wn+j*16+quad*4+r]: 4 consecutive cols -> packed store.
// ---------------------------------------------------------------------------
template <typename OT>
__global__ __launch_bounds__(256) void gemm_bt(
    const bf16_t* __restrict__ A, const bf16_t* __restrict__ B,
    const float* __restrict__ bias, OT* __restrict__ C, int M, int N, int K) {
  __shared__ bf16_t As[128 * 64];
  __shared__ bf16_t Bs[128 * 64];
  const int tid = threadIdx.x;
  const int wave = tid >> 6;
  const int lane = tid & 63;
  const int quad = lane >> 4;
  const int l16 = lane & 15;
  const int m0 = blockIdx.x * 128;
  const int n0 = blockIdx.y * 128;
  const int wm = (wave >> 1) * 64;
  const int wn = (wave & 1) * 64;

  // staging map: issue t covers LDS granules [wave*256+t*64, +64);
  // lane -> row r0 + t*8 (r0 = wave*32 + lane>>3), src granule (lane&7)^(r0&7)
  const int r0 = wave * 32 + (lane >> 3);
  const int g = ((lane & 7) ^ (r0 & 7)) * 8;  // element offset in row
  const bf16_t* Ab = A + (size_t)(m0 + r0) * K + g;
  const bf16_t* Bb = B + (size_t)(n0 + r0) * K + g;

  // fragment read offset (elements) for ks=0; ks=1 is ^32
  const int p0 = ((quad ^ (l16 & 7))) * 8;

  floatx4 acc[4][4];
  const floatx4 zf = {0.f, 0.f, 0.f, 0.f};
#pragma unroll
  for (int i = 0; i < 4; ++i)
#pragma unroll
    for (int j = 0; j < 4; ++j) acc[i][j] = zf;

  for (int k0 = 0; k0 < K; k0 += 64) {
#pragma unroll
    for (int t = 0; t < 4; ++t) {
      GLDS16(Ab + (size_t)(t * 8) * K + k0, As + (wave * 256 + t * 64) * 8);
      GLDS16(Bb + (size_t)(t * 8) * K + k0, Bs + (wave * 256 + t * 64) * 8);
    }
    __syncthreads();
#pragma unroll
    for (int ks = 0; ks < 2; ++ks) {
      const int ko = p0 ^ (ks * 32);
      bf16x8 af[4], bfr[4];
#pragma unroll
      for (int i = 0; i < 4; ++i)
        af[i] = *(const bf16x8*)(As + (wm + i * 16 + l16) * 64 + ko);
#pragma unroll
      for (int j = 0; j < 4; ++j)
        bfr[j] = *(const bf16x8*)(Bs + (wn + j * 16 + l16) * 64 + ko);
#pragma unroll
      for (int i = 0; i < 4; ++i)
#pragma unroll
        for (int j = 0; j < 4; ++j)
          acc[i][j] = __builtin_amdgcn_mfma_f32_16x16x32_bf16(
              bfr[j], af[i], acc[i][j], 0, 0, 0);
    }
    __syncthreads();
  }

#pragma unroll
  for (int j = 0; j < 4; ++j) {
    const int colb = n0 + wn + j * 16 + quad * 4;
    floatx4 bv = zf;
    if (bias) bv = *(const floatx4*)(bias + colb);
#pragma unroll
    for (int i = 0; i < 4; ++i) {
      const int row = m0 + wm + i * 16 + l16;
      floatx4 v = acc[i][j] + bv;
      if constexpr (sizeof(OT) == 4) {
        *(floatx4*)((float*)C + (size_t)row * N + colb) = v;
      } else {
        union {
          bf16_t b[4];
          uint32_t u[2];
        } pk;
        pk.b[0] = (bf16_t)v[0];
        pk.b[1] = (bf16_t)v[1];
        pk.b[2] = (bf16_t)v[2];
        pk.b[3] = (bf16_t)v[3];
        uint32_t* dst = (uint32_t*)((bf16_t*)C + (size_t)row * N + colb);
        dst[0] = pk.u[0];
        dst[1] = pk.u[1];
      }
    }
  }
}

// ---------------------------------------------------------------------------
// One prep kernel: all fp32->bf16 converts + bias assembly.
// blocks: [0,8192) x | [8192,11264) Wqkv | [11264,12288) Wpw |
// [12288,13312) Wout->Wbig2 | [13312,14336) Wtw->Wbig2+1024 |
// [14336,14339) bqkv->bias1 | 14339 bias2 = bout+btw
// ---------------------------------------------------------------------------
__global__ __launch_bounds__(256) void prep_k(
    const float* __restrict__ x, bf16_t* __restrict__ x_bf,
    const float* __restrict__ Wqkv, bf16_t* __restrict__ Wbig1,
    const float* __restrict__ Wpw, bf16_t* __restrict__ Wpw_bf,
    const float* __restrict__ Wout, const float* __restrict__ Wtw,
    bf16_t* __restrict__ Wbig2, const float* __restrict__ bqkv,
    float* __restrict__ bias1, const float* __restrict__ bout,
    const float* __restrict__ btw, float* __restrict__ bias2) {
  const int b = blockIdx.x, tid = threadIdx.x;
  auto cvt4 = [](const float* in, bf16_t* out, int i) {
    floatx4 v = ((const floatx4*)in)[i];
    bf16x4 o;
    o[0] = (bf16_t)v[0];
    o[1] = (bf16_t)v[1];
    o[2] = (bf16_t)v[2];
    o[3] = (bf16_t)v[3];
    ((bf16x4*)out)[i] = o;
  };
  if (b < 8192) {
    cvt4(x, x_bf, b * 256 + tid);
  } else if (b < 11264) {
    cvt4(Wqkv, Wbig1, (b - 8192) * 256 + tid);
  } else if (b < 12288) {
    cvt4(Wpw, Wpw_bf, (b - 11264) * 256 + tid);
  } else if (b < 14336) {
    const bool second = b >= 13312;
    int i = (b - (second ? 13312 : 12288)) * 256 + tid;
    floatx4 v = ((const floatx4*)(second ? Wtw : Wout))[i];
    bf16x4 o;
    o[0] = (bf16_t)v[0];
    o[1] = (bf16_t)v[1];
    o[2] = (bf16_t)v[2];
    o[3] = (bf16_t)v[3];
    int row = i >> 8, c4 = i & 255;
    *(bf16x4*)(Wbig2 + (size_t)row * 2048 + (second ? 1024 : 0) + c4 * 4) = o;
  } else if (b < 14339) {
    int i = (b - 14336) * 256 + tid;
    if (i < 768) ((floatx4*)bias1)[i] = ((const floatx4*)bqkv)[i];
  } else {
    ((floatx4*)bias2)[tid] =
        ((const floatx4*)bout)[tid] + ((const floatx4*)btw)[tid];
  }
}

// W_cp (1024x1024 fp32) -> W_cp^T bf16
__global__ __launch_bounds__(256) void transpose_cvt_k(
    const float* __restrict__ in, bf16_t* __restrict__ out) {
  __shared__ float t[32][33];
  const int bx = blockIdx.x * 32, by = blockIdx.y * 32;
  const int tx = threadIdx.x, ty = threadIdx.y;
#pragma unroll
  for (int i = 0; i < 32; i += 8)
    t[ty + i][tx] = in[(size_t)(by + ty + i) * 1024 + bx + tx];
  __syncthreads();
#pragma unroll
  for (int i = 0; i < 32; i += 8)
    out[(size_t)(bx + ty + i) * 1024 + by + tx] = (bf16_t)t[tx][ty + i];
}

// b_comb = W_pw @ b_cp + b_pw  -> bias1+3072
__global__ __launch_bounds__(64) void bcomb_k(const float* __restrict__ Wpw,
                                              const float* __restrict__ bcp,
                                              const float* __restrict__ bpw,
                                              float* __restrict__ outb) {
  const int i = blockIdx.x;
  const int l = threadIdx.x;
  const float* row = Wpw + (size_t)i * 1024;
  float s = 0.f;
  for (int j = l; j < 1024; j += 64) s += row[j] * bcp[j];
#pragma unroll
  for (int o = 32; o > 0; o >>= 1) s += __shfl_down(s, o);
  if (l == 0) outb[i] = s + bpw[i];
}

static __device__ inline void exp8(uint32_t w0, uint32_t w1, uint32_t w2,
                                   uint32_t w3, float* f) {
  f[0] = __uint_as_float(w0 << 16);
  f[1] = __uint_as_float(w0 & 0xffff0000u);
  f[2] = __uint_as_float(w1 << 16);
  f[3] = __uint_as_float(w1 & 0xffff0000u);
  f[4] = __uint_as_float(w2 << 16);
  f[5] = __uint_as_float(w2 & 0xffff0000u);
  f[6] = __uint_as_float(w3 << 16);
  f[7] = __uint_as_float(w3 & 0xffff0000u);
}

// ---------------------------------------------------------------------------
// Attention-over-heads: per token, Q,K,V 16x64, scores 16x16, softmax, P@V.
// One wave per token; uint4 global loads, fp32 LDS.
// ---------------------------------------------------------------------------
__global__ __launch_bounds__(256) void attn_k(const bf16_t* __restrict__ qkv,
                                              const float* __restrict__ pos,
                                              bf16_t* __restrict__ outp,
                                              int qstride, int ostride) {
  __shared__ float sh[4 * 3264 + 4 * 272];
  const int tid = threadIdx.x;
  const int wave = tid >> 6, lane = tid & 63;
  const int p = blockIdx.x * 4 + wave;
  float* shw = sh + wave * 3264;
  float* pl = sh + 4 * 3264 + wave * 272;

  const uint4* src = (const uint4*)(qkv + (size_t)p * qstride);
#pragma unroll
  for (int i = 0; i < 6; ++i) {
    uint4 w = src[lane + i * 64];
    int c0 = 8 * (lane + i * 64);
    int h = c0 / 192;
    int rem = c0 - h * 192;
    int role = rem >> 6, d0 = rem & 63;
    float f[8];
    exp8(w.x, w.y, w.z, w.w, f);
    float* dst = shw + (h * 3 + role) * 68 + d0;
    *(floatx4*)dst = *(floatx4*)f;
    *(floatx4*)(dst + 4) = *(floatx4*)(f + 4);
  }
  __syncthreads();

  const int l16 = lane & 15, quad = lane >> 4;
  const int h = l16, g0 = quad * 4;
  const float* qrow = shw + h * 204;
  const float* krow = shw + (g0 * 3 + 1) * 68;
  const floatx4 zf = {0.f, 0.f, 0.f, 0.f};
  floatx4 s4[4] = {zf, zf, zf, zf};
  for (int d = 0; d < 64; d += 4) {
    floatx4 qv = *(const floatx4*)(qrow + d);
    s4[0] += qv * *(const floatx4*)(krow + d);
    s4[1] += qv * *(const floatx4*)(krow + 204 + d);
    s4[2] += qv * *(const floatx4*)(krow + 408 + d);
    s4[3] += qv * *(const floatx4*)(krow + 612 + d);
  }
  const float* pb = pos + (size_t)(p & 2047) * 256 + h * 16 + g0;
  float s[4];
#pragma unroll
  for (int jj = 0; jj < 4; ++jj)
    s[jj] = (s4[jj][0] + s4[jj][1] + s4[jj][2] + s4[jj][3]) * 0.125f + pb[jj];

  float m = fmaxf(fmaxf(s[0], s[1]), fmaxf(s[2], s[3]));
  m = fmaxf(m, __shfl_xor(m, 16));
  m = fmaxf(m, __shfl_xor(m, 32));
  float e[4], sum = 0.f;
#pragma unroll
  for (int jj = 0; jj < 4; ++jj) {
    e[jj] = __expf(s[jj] - m);
    sum += e[jj];
  }
  sum += __shfl_xor(sum, 16);
  sum += __shfl_xor(sum, 32);
  const float inv = 1.0f / sum;
#pragma unroll
  for (int jj = 0; jj < 4; ++jj) pl[h * 17 + g0 + jj] = e[jj] * inv;
  __syncthreads();

  const int h2 = lane >> 2, dbase = (lane & 3) * 16;
  floatx4 o0 = zf, o1 = zf, o2 = zf, o3 = zf;
  for (int g = 0; g < 16; ++g) {
    float pw = pl[h2 * 17 + g];
    const float* vr = shw + g * 204 + 136 + dbase;
    o0 += pw * *(const floatx4*)(vr);
    o1 += pw * *(const floatx4*)(vr + 4);
    o2 += pw * *(const floatx4*)(vr + 8);
    o3 += pw * *(const floatx4*)(vr + 12);
  }
  union {
    bf16_t b[16];
    uint4 u4[2];
  } pk;
#pragma unroll
  for (int t2 = 0; t2 < 4; ++t2) {
    pk.b[t2] = (bf16_t)o0[t2];
    pk.b[4 + t2] = (bf16_t)o1[t2];
    pk.b[8 + t2] = (bf16_t)o2[t2];
    pk.b[12 + t2] = (bf16_t)o3[t2];
  }
  uint4* dst = (uint4*)(outp + (size_t)p * ostride + h2 * 64 + dbase);
  dst[0] = pk.u4[0];
  dst[1] = pk.u4[1];
}

// ---------------------------------------------------------------------------
// Depthwise conv k=3 over seq; in row-stride 4096 (pre-offset to conv cols),
// out row-stride 2048 (pre-offset to second K-half). 1024 blocks; item ->
// cc = 8-col chunk (coalesced across lanes), 4 rows per thread.
// ---------------------------------------------------------------------------
__global__ __launch_bounds__(256) void dwconv_k(const bf16_t* __restrict__ in,
                                                const float* __restrict__ Wdw,
                                                const float* __restrict__ bdw,
                                                bf16_t* __restrict__ out) {
  const int item = blockIdx.x * 256 + threadIdx.x;  // 262144
  const int cc = item & 127, rowg = item >> 7;
  const int c0 = cc * 8;
  float w0[8], w1[8], w2[8], bb[8];
#pragma unroll
  for (int c = 0; c < 8; ++c) {
    w0[c] = Wdw[(c0 + c) * 3];
    w1[c] = Wdw[(c0 + c) * 3 + 1];
    w2[c] = Wdw[(c0 + c) * 3 + 2];
    bb[c] = bdw[c0 + c];
  }
#pragma unroll
  for (int jr = 0; jr < 4; ++jr) {
    const int t = rowg * 4 + jr;
    const int n = t & 2047;
    const bf16_t* ip = in + (size_t)t * 4096 + c0;
    const uint4 z4 = {0, 0, 0, 0};
    uint4 um = (n > 0) ? *(const uint4*)(ip - 4096) : z4;
    uint4 uc = *(const uint4*)(ip);
    uint4 up = (n < 2047) ? *(const uint4*)(ip + 4096) : z4;
    float fm[8], fc[8], fp[8];
    exp8(um.x, um.y, um.z, um.w, fm);
    exp8(uc.x, uc.y, uc.z, uc.w, fc);
    exp8(up.x, up.y, up.z, up.w, fp);
    union {
      bf16_t b[8];
      uint4 u;
    } pk;
#pragma unroll
    for (int c = 0; c < 8; ++c)
      pk.b[c] = (bf16_t)(bb[c] + fm[c] * w0[c] + fc[c] * w1[c] + fp[c] * w2[c]);
    *(uint4*)(out + (size_t)t * 2048 + c0) = pk.u;
  }
}

// ---------------------------------------------------------------------------
extern "C" void kernel_launch(void* const* d_in, const int* in_sizes, int n_in,
                              void* d_out, int out_size, void* d_ws,
                              size_t ws_size, hipStream_t stream) {
  (void)in_sizes; (void)n_in; (void)out_size; (void)ws_size;
  const float* x = (const float*)d_in[0];
  const float* Wqkv = (const float*)d_in[1];
  const float* bqkv = (const float*)d_in[2];
  const float* Wout = (const float*)d_in[3];
  const float* bout = (const float*)d_in[4];
  const float* pos = (const float*)d_in[5];
  const float* Wcp = (const float*)d_in[6];
  const float* bcp = (const float*)d_in[7];
  const float* Wpw = (const float*)d_in[8];
  const float* bpw = (const float*)d_in[9];
  const float* Wdw = (const float*)d_in[10];
  const float* bdw = (const float*)d_in[11];
  const float* Wtw = (const float*)d_in[12];
  const float* btw = (const float*)d_in[13];
  float* out = (float*)d_out;

  char* ws = (char*)d_ws;
  const size_t MB = 1024ull * 1024ull;
  bf16_t* x_bf = (bf16_t*)(ws + 0);              // 16 MB (dead after GEMM1)
  bf16_t* Wbig1 = (bf16_t*)(ws + 16 * MB);       // 8 MB: [Wqkv ; Wcomb]
  bf16_t* WcpT = (bf16_t*)(ws + 24 * MB);        // 2 MB
  bf16_t* Wpw_bf = (bf16_t*)(ws + 26 * MB);      // 2 MB
  bf16_t* Mid = (bf16_t*)(ws + 0);               // 32 MB (after GEMM1)
  bf16_t* Wbig2 = (bf16_t*)(ws + 32 * MB);       // 4 MB: [Wout|Wtw] K-concat
  float* bias1 = (float*)(ws + 36 * MB);         // 16 KB
  float* bias2 = (float*)(ws + 36 * MB + 65536); // 4 KB
  bf16_t* G1out = (bf16_t*)(ws + 37 * MB);       // 64 MB: 8192 x 4096

  prep_k<<<14340, 256, 0, stream>>>(x, x_bf, Wqkv, Wbig1, Wpw, Wpw_bf, Wout,
                                    Wtw, Wbig2, bqkv, bias1, bout, btw, bias2);
  transpose_cvt_k<<<dim3(32, 32), dim3(32, 8), 0, stream>>>(Wcp, WcpT);
  bcomb_k<<<1024, 64, 0, stream>>>(Wpw, bcp, bpw, bias1 + 3072);

  // W_comb = W_pw @ W_cp -> rows 3072..4095 of Wbig1
  gemm_bt<bf16_t><<<dim3(8, 8), 256, 0, stream>>>(
      Wpw_bf, WcpT, nullptr, Wbig1 + (size_t)3072 * 1024, 1024, 1024, 1024);

  // GEMM1: x @ [Wqkv ; Wcomb]^T + [bqkv ; bcomb] -> 8192 x 4096
  gemm_bt<bf16_t><<<dim3(64, 32), 256, 0, stream>>>(
      x_bf, Wbig1, bias1, G1out, 8192, 4096, 1024);

  // attention (cols 0..3071) -> Mid cols 0..1023
  attn_k<<<2048, 256, 0, stream>>>(G1out, pos, Mid, 4096, 2048);
  // depthwise conv on cols 3072..4095 -> Mid cols 1024..2047
  dwconv_k<<<1024, 256, 0, stream>>>(G1out + 3072, Wdw, bdw, Mid + 1024);

  // GEMM2: [attn|dwc] @ [Wout|Wtw]^T + (bout+btw) -> out (fp32)
  gemm_bt<float><<<dim3(64, 8), 256, 0, stream>>>(Mid, Wbig2, bias2, out,
                                                  8192, 1024, 2048);
}

// Round 4
// 295.592 us; speedup vs baseline: 1.2609x; 1.0473x over previous
//
#include <hip/hip_runtime.h>
#include <hip/hip_bf16.h>
#include <stdint.h>

// B=4, N=2048, C=1024, H=16, HD=64; 8192 token rows.
typedef __bf16 bf16_t;
typedef __attribute__((ext_vector_type(8))) __bf16 bf16x8;
typedef __attribute__((ext_vector_type(4))) __bf16 bf16x4;
typedef __attribute__((ext_vector_type(4))) float floatx4;
typedef __attribute__((ext_vector_type(4))) _Float16 half4_t;

#define GLDS16(g, l)                                                          \
  __builtin_amdgcn_global_load_lds(                                           \
      (const __attribute__((address_space(1))) void*)(g),                     \
      (__attribute__((address_space(3))) void*)(l), 16, 0, 0)

// ---------------------------------------------------------------------------
// C[M,N] = A[M,K] @ B[N,K]^T (+ bias[N]); bf16 in, fp32 acc.
// 128x128 tile, BK=64 (32 KB LDS), 4 waves 2x2, 4x4 MFMA tiles/wave.
// K-loop staging XOR-swizzled (round-3, conflicts measured 0).
// bf16 epilogue: stage output tile in LDS (even-XOR granule swizzle keeps
// 16B pairs adjacent), read back row-major, store 16B/lane -> 256B/row
// segments (fixes 32B-segment HBM read-modify-write amplification).
// ---------------------------------------------------------------------------
template <typename OT>
__global__ __launch_bounds__(256) void gemm_bt(
    const bf16_t* __restrict__ A, const bf16_t* __restrict__ B,
    const float* __restrict__ bias, OT* __restrict__ C, int M, int N, int K) {
  __shared__ bf16_t sm[128 * 128];  // K-loop: As = sm, Bs = sm + 128*64
  bf16_t* As = sm;
  bf16_t* Bs = sm + 128 * 64;
  const int tid = threadIdx.x;
  const int wave = tid >> 6;
  const int lane = tid & 63;
  const int quad = lane >> 4;
  const int l16 = lane & 15;
  const int m0 = blockIdx.x * 128;
  const int n0 = blockIdx.y * 128;
  const int wm = (wave >> 1) * 64;
  const int wn = (wave & 1) * 64;

  const int r0 = wave * 32 + (lane >> 3);
  const int g = ((lane & 7) ^ (r0 & 7)) * 8;
  const bf16_t* Ab = A + (size_t)(m0 + r0) * K + g;
  const bf16_t* Bb = B + (size_t)(n0 + r0) * K + g;
  const int p0 = ((quad ^ (l16 & 7))) * 8;

  floatx4 acc[4][4];
  const floatx4 zf = {0.f, 0.f, 0.f, 0.f};
#pragma unroll
  for (int i = 0; i < 4; ++i)
#pragma unroll
    for (int j = 0; j < 4; ++j) acc[i][j] = zf;

  for (int k0 = 0; k0 < K; k0 += 64) {
#pragma unroll
    for (int t = 0; t < 4; ++t) {
      GLDS16(Ab + (size_t)(t * 8) * K + k0, As + (wave * 256 + t * 64) * 8);
      GLDS16(Bb + (size_t)(t * 8) * K + k0, Bs + (wave * 256 + t * 64) * 8);
    }
    __syncthreads();
#pragma unroll
    for (int ks = 0; ks < 2; ++ks) {
      const int ko = p0 ^ (ks * 32);
      bf16x8 af[4], bfr[4];
#pragma unroll
      for (int i = 0; i < 4; ++i)
        af[i] = *(const bf16x8*)(As + (wm + i * 16 + l16) * 64 + ko);
#pragma unroll
      for (int j = 0; j < 4; ++j)
        bfr[j] = *(const bf16x8*)(Bs + (wn + j * 16 + l16) * 64 + ko);
#pragma unroll
      for (int i = 0; i < 4; ++i)
#pragma unroll
        for (int j = 0; j < 4; ++j)
          acc[i][j] = __builtin_amdgcn_mfma_f32_16x16x32_bf16(
              bfr[j], af[i], acc[i][j], 0, 0, 0);
    }
    __syncthreads();
  }

  if constexpr (sizeof(OT) == 4) {
    // fp32: direct packed stores (64B/row segments — clean)
#pragma unroll
    for (int j = 0; j < 4; ++j) {
      const int colb = n0 + wn + j * 16 + quad * 4;
      floatx4 bv = zf;
      if (bias) bv = *(const floatx4*)(bias + colb);
#pragma unroll
      for (int i = 0; i < 4; ++i) {
        const int row = m0 + wm + i * 16 + l16;
        floatx4 v = acc[i][j] + bv;
        *(floatx4*)((float*)C + (size_t)row * N + colb) = v;
      }
    }
  } else {
    // bf16: LDS round-trip for coalesced 16B/lane stores.
    // granule = 8B (4 bf16); element (rl, cl) stored at granule
    // (cl>>2) ^ (4*(rl&7)) of row rl.  XOR with multiple of 4 keeps 16B
    // granule-pairs adjacent for the read-back.
#pragma unroll
    for (int j = 0; j < 4; ++j) {
      const int colb = n0 + wn + j * 16 + quad * 4;
      floatx4 bv = zf;
      if (bias) bv = *(const floatx4*)(bias + colb);
      const int gcol = ((wn + j * 16 + quad * 4) >> 2);
#pragma unroll
      for (int i = 0; i < 4; ++i) {
        const int rl = wm + i * 16 + l16;
        floatx4 v = acc[i][j] + bv;
        union {
          bf16_t b[4];
          uint2 u2;
        } pk;
        pk.b[0] = (bf16_t)v[0];
        pk.b[1] = (bf16_t)v[1];
        pk.b[2] = (bf16_t)v[2];
        pk.b[3] = (bf16_t)v[3];
        const int gsw = gcol ^ ((rl & 7) * 4);
        *(uint2*)(sm + rl * 128 + gsw * 4) = pk.u2;
      }
    }
    __syncthreads();
    bf16_t* Cb = (bf16_t*)C;
#pragma unroll
    for (int pass = 0; pass < 8; ++pass) {
      const int f = pass * 256 + tid;  // 0..2047
      const int row = f >> 4;          // 0..127
      const int c16 = f & 15;          // 16B chunk within row
      const int g0 = (2 * c16) ^ ((row & 7) * 4);
      uint4 v = *(const uint4*)(sm + row * 128 + g0 * 4);
      *(uint4*)(Cb + (size_t)(m0 + row) * N + n0 + c16 * 8) = v;
    }
  }
}

// ---------------------------------------------------------------------------
// One prep kernel: all fp32->bf16 converts + bias assembly.
// ---------------------------------------------------------------------------
__global__ __launch_bounds__(256) void prep_k(
    const float* __restrict__ x, bf16_t* __restrict__ x_bf,
    const float* __restrict__ Wqkv, bf16_t* __restrict__ Wbig1,
    const float* __restrict__ Wpw, bf16_t* __restrict__ Wpw_bf,
    const float* __restrict__ Wout, const float* __restrict__ Wtw,
    bf16_t* __restrict__ Wbig2, const float* __restrict__ bqkv,
    float* __restrict__ bias1, const float* __restrict__ bout,
    const float* __restrict__ btw, float* __restrict__ bias2) {
  const int b = blockIdx.x, tid = threadIdx.x;
  auto cvt4 = [](const float* in, bf16_t* out, int i) {
    floatx4 v = ((const floatx4*)in)[i];
    bf16x4 o;
    o[0] = (bf16_t)v[0];
    o[1] = (bf16_t)v[1];
    o[2] = (bf16_t)v[2];
    o[3] = (bf16_t)v[3];
    ((bf16x4*)out)[i] = o;
  };
  if (b < 8192) {
    cvt4(x, x_bf, b * 256 + tid);
  } else if (b < 11264) {
    cvt4(Wqkv, Wbig1, (b - 8192) * 256 + tid);
  } else if (b < 12288) {
    cvt4(Wpw, Wpw_bf, (b - 11264) * 256 + tid);
  } else if (b < 14336) {
    const bool second = b >= 13312;
    int i = (b - (second ? 13312 : 12288)) * 256 + tid;
    floatx4 v = ((const floatx4*)(second ? Wtw : Wout))[i];
    bf16x4 o;
    o[0] = (bf16_t)v[0];
    o[1] = (bf16_t)v[1];
    o[2] = (bf16_t)v[2];
    o[3] = (bf16_t)v[3];
    int row = i >> 8, c4 = i & 255;
    *(bf16x4*)(Wbig2 + (size_t)row * 2048 + (second ? 1024 : 0) + c4 * 4) = o;
  } else if (b < 14339) {
    int i = (b - 14336) * 256 + tid;
    if (i < 768) ((floatx4*)bias1)[i] = ((const floatx4*)bqkv)[i];
  } else {
    ((floatx4*)bias2)[tid] =
        ((const floatx4*)bout)[tid] + ((const floatx4*)btw)[tid];
  }
}

// W_cp (1024x1024 fp32) -> W_cp^T bf16
__global__ __launch_bounds__(256) void transpose_cvt_k(
    const float* __restrict__ in, bf16_t* __restrict__ out) {
  __shared__ float t[32][33];
  const int bx = blockIdx.x * 32, by = blockIdx.y * 32;
  const int tx = threadIdx.x, ty = threadIdx.y;
#pragma unroll
  for (int i = 0; i < 32; i += 8)
    t[ty + i][tx] = in[(size_t)(by + ty + i) * 1024 + bx + tx];
  __syncthreads();
#pragma unroll
  for (int i = 0; i < 32; i += 8)
    out[(size_t)(bx + ty + i) * 1024 + by + tx] = (bf16_t)t[tx][ty + i];
}

// b_comb = W_pw @ b_cp + b_pw  -> bias1+3072
__global__ __launch_bounds__(64) void bcomb_k(const float* __restrict__ Wpw,
                                              const float* __restrict__ bcp,
                                              const float* __restrict__ bpw,
                                              float* __restrict__ outb) {
  const int i = blockIdx.x;
  const int l = threadIdx.x;
  const float* row = Wpw + (size_t)i * 1024;
  float s = 0.f;
  for (int j = l; j < 1024; j += 64) s += row[j] * bcp[j];
#pragma unroll
  for (int o = 32; o > 0; o >>= 1) s += __shfl_down(s, o);
  if (l == 0) outb[i] = s + bpw[i];
}

// ---------------------------------------------------------------------------
// MFMA attention-over-heads, zero LDS. One wave per token.
// qkv row layout: channel c = h*192 + role*64 + d (role 0=Q,1=K,2=V).
// QK^T: S[g][h] via mfma_16x16x32_bf16(A=Kfrag, B=Qfrag) x2 (d-halves);
//   fragments are direct 16B global loads.
// D layout: reg r -> S[g=quad*4+r][h=l16]. pos bias = floatx4 per lane.
// softmax over g: 4-reg fold + shfl_xor(16,32).
// P[h=l16][g=quad*4+r] == A-frag of mfma_f32_16x16x16f16 (fp16, P in [0,1]).
// PV: 4 MFMAs over d-tiles, V fragments scalar-loaded, D[h][d] stored bf16.
// ---------------------------------------------------------------------------
__global__ __launch_bounds__(256) void attn_k(const bf16_t* __restrict__ qkv,
                                              const float* __restrict__ pos,
                                              bf16_t* __restrict__ outp) {
  const int tid = threadIdx.x;
  const int wave = tid >> 6, lane = tid & 63;
  const int p = blockIdx.x * 4 + wave;
  const int l16 = lane & 15, quad = lane >> 4;
  const bf16_t* row = qkv + (size_t)p * 4096;
  const bf16_t* qb = row + l16 * 192 + quad * 8;

  bf16x8 q0 = *(const bf16x8*)(qb);
  bf16x8 q1 = *(const bf16x8*)(qb + 32);
  bf16x8 k0 = *(const bf16x8*)(qb + 64);
  bf16x8 k1 = *(const bf16x8*)(qb + 96);
  floatx4 S = {0.f, 0.f, 0.f, 0.f};
  S = __builtin_amdgcn_mfma_f32_16x16x32_bf16(k0, q0, S, 0, 0, 0);
  S = __builtin_amdgcn_mfma_f32_16x16x32_bf16(k1, q1, S, 0, 0, 0);

  const floatx4 pb =
      *(const floatx4*)(pos + (size_t)(p & 2047) * 256 + l16 * 16 + quad * 4);
  float v[4];
#pragma unroll
  for (int r = 0; r < 4; ++r) v[r] = S[r] * 0.125f + pb[r];

  float m = fmaxf(fmaxf(v[0], v[1]), fmaxf(v[2], v[3]));
  m = fmaxf(m, __shfl_xor(m, 16));
  m = fmaxf(m, __shfl_xor(m, 32));
  float e[4], sum = 0.f;
#pragma unroll
  for (int r = 0; r < 4; ++r) {
    e[r] = __expf(v[r] - m);
    sum += e[r];
  }
  sum += __shfl_xor(sum, 16);
  sum += __shfl_xor(sum, 32);
  const float inv = 1.0f / sum;
  half4_t pa;
#pragma unroll
  for (int r = 0; r < 4; ++r) pa[r] = (_Float16)(e[r] * inv);

  const bf16_t* vb_base = row + 128 + l16;  // + g*192 + t*16
  const floatx4 zf = {0.f, 0.f, 0.f, 0.f};
  floatx4 o[4];
#pragma unroll
  for (int t = 0; t < 4; ++t) {
    half4_t vb;
#pragma unroll
    for (int j = 0; j < 4; ++j)
      vb[j] = (_Float16)(float)vb_base[(quad * 4 + j) * 192 + t * 16];
    o[t] = __builtin_amdgcn_mfma_f32_16x16x16f16(pa, vb, zf, 0, 0, 0);
  }

  bf16_t* ob = outp + (size_t)p * 2048 + (quad * 4) * 64 + l16;
#pragma unroll
  for (int r = 0; r < 4; ++r)
#pragma unroll
    for (int t = 0; t < 4; ++t) ob[r * 64 + t * 16] = (bf16_t)o[t][r];
}

static __device__ inline void exp8(uint32_t w0, uint32_t w1, uint32_t w2,
                                   uint32_t w3, float* f) {
  f[0] = __uint_as_float(w0 << 16);
  f[1] = __uint_as_float(w0 & 0xffff0000u);
  f[2] = __uint_as_float(w1 << 16);
  f[3] = __uint_as_float(w1 & 0xffff0000u);
  f[4] = __uint_as_float(w2 << 16);
  f[5] = __uint_as_float(w2 & 0xffff0000u);
  f[6] = __uint_as_float(w3 << 16);
  f[7] = __uint_as_float(w3 & 0xffff0000u);
}

// ---------------------------------------------------------------------------
// Depthwise conv k=3 over seq; in row-stride 4096 (pre-offset to conv cols),
// out row-stride 2048 (pre-offset to second K-half).
// ---------------------------------------------------------------------------
__global__ __launch_bounds__(256) void dwconv_k(const bf16_t* __restrict__ in,
                                                const float* __restrict__ Wdw,
                                                const float* __restrict__ bdw,
                                                bf16_t* __restrict__ out) {
  const int item = blockIdx.x * 256 + threadIdx.x;  // 262144
  const int cc = item & 127, rowg = item >> 7;
  const int c0 = cc * 8;
  float w0[8], w1[8], w2[8], bb[8];
#pragma unroll
  for (int c = 0; c < 8; ++c) {
    w0[c] = Wdw[(c0 + c) * 3];
    w1[c] = Wdw[(c0 + c) * 3 + 1];
    w2[c] = Wdw[(c0 + c) * 3 + 2];
    bb[c] = bdw[c0 + c];
  }
#pragma unroll
  for (int jr = 0; jr < 4; ++jr) {
    const int t = rowg * 4 + jr;
    const int n = t & 2047;
    const bf16_t* ip = in + (size_t)t * 4096 + c0;
    const uint4 z4 = {0, 0, 0, 0};
    uint4 um = (n > 0) ? *(const uint4*)(ip - 4096) : z4;
    uint4 uc = *(const uint4*)(ip);
    uint4 up = (n < 2047) ? *(const uint4*)(ip + 4096) : z4;
    float fm[8], fc[8], fp[8];
    exp8(um.x, um.y, um.z, um.w, fm);
    exp8(uc.x, uc.y, uc.z, uc.w, fc);
    exp8(up.x, up.y, up.z, up.w, fp);
    union {
      bf16_t b[8];
      uint4 u;
    } pk;
#pragma unroll
    for (int c = 0; c < 8; ++c)
      pk.b[c] = (bf16_t)(bb[c] + fm[c] * w0[c] + fc[c] * w1[c] + fp[c] * w2[c]);
    *(uint4*)(out + (size_t)t * 2048 + c0) = pk.u;
  }
}

// ---------------------------------------------------------------------------
extern "C" void kernel_launch(void* const* d_in, const int* in_sizes, int n_in,
                              void* d_out, int out_size, void* d_ws,
                              size_t ws_size, hipStream_t stream) {
  (void)in_sizes; (void)n_in; (void)out_size; (void)ws_size;
  const float* x = (const float*)d_in[0];
  const float* Wqkv = (const float*)d_in[1];
  const float* bqkv = (const float*)d_in[2];
  const float* Wout = (const float*)d_in[3];
  const float* bout = (const float*)d_in[4];
  const float* pos = (const float*)d_in[5];
  const float* Wcp = (const float*)d_in[6];
  const float* bcp = (const float*)d_in[7];
  const float* Wpw = (const float*)d_in[8];
  const float* bpw = (const float*)d_in[9];
  const float* Wdw = (const float*)d_in[10];
  const float* bdw = (const float*)d_in[11];
  const float* Wtw = (const float*)d_in[12];
  const float* btw = (const float*)d_in[13];
  float* out = (float*)d_out;

  char* ws = (char*)d_ws;
  const size_t MB = 1024ull * 1024ull;
  bf16_t* x_bf = (bf16_t*)(ws + 0);              // 16 MB (dead after GEMM1)
  bf16_t* Wbig1 = (bf16_t*)(ws + 16 * MB);       // 8 MB: [Wqkv ; Wcomb]
  bf16_t* WcpT = (bf16_t*)(ws + 24 * MB);        // 2 MB
  bf16_t* Wpw_bf = (bf16_t*)(ws + 26 * MB);      // 2 MB
  bf16_t* Mid = (bf16_t*)(ws + 0);               // 32 MB (after GEMM1)
  bf16_t* Wbig2 = (bf16_t*)(ws + 32 * MB);       // 4 MB: [Wout|Wtw] K-concat
  float* bias1 = (float*)(ws + 36 * MB);         // 16 KB
  float* bias2 = (float*)(ws + 36 * MB + 65536); // 4 KB
  bf16_t* G1out = (bf16_t*)(ws + 37 * MB);       // 64 MB: 8192 x 4096

  prep_k<<<14340, 256, 0, stream>>>(x, x_bf, Wqkv, Wbig1, Wpw, Wpw_bf, Wout,
                                    Wtw, Wbig2, bqkv, bias1, bout, btw, bias2);
  transpose_cvt_k<<<dim3(32, 32), dim3(32, 8), 0, stream>>>(Wcp, WcpT);
  bcomb_k<<<1024, 64, 0, stream>>>(Wpw, bcp, bpw, bias1 + 3072);

  // W_comb = W_pw @ W_cp -> rows 3072..4095 of Wbig1
  gemm_bt<bf16_t><<<dim3(8, 8), 256, 0, stream>>>(
      Wpw_bf, WcpT, nullptr, Wbig1 + (size_t)3072 * 1024, 1024, 1024, 1024);

  // GEMM1: x @ [Wqkv ; Wcomb]^T + [bqkv ; bcomb] -> 8192 x 4096
  gemm_bt<bf16_t><<<dim3(64, 32), 256, 0, stream>>>(
      x_bf, Wbig1, bias1, G1out, 8192, 4096, 1024);

  // attention (cols 0..3071) -> Mid cols 0..1023
  attn_k<<<2048, 256, 0, stream>>>(G1out, pos, Mid);
  // depthwise conv on cols 3072..4095 -> Mid cols 1024..2047
  dwconv_k<<<1024, 256, 0, stream>>>(G1out + 3072, Wdw, bdw, Mid + 1024);

  // GEMM2: [attn|dwc] @ [Wout|Wtw]^T + (bout+btw) -> out (fp32)
  gemm_bt<float><<<dim3(64, 8), 256, 0, stream>>>(Mid, Wbig2, bias2, out,
                                                  8192, 1024, 2048);
}

// Round 5
// 278.932 us; speedup vs baseline: 1.3362x; 1.0597x over previous
//
#include <hip/hip_runtime.h>
#include <hip/hip_bf16.h>
#include <stdint.h>

// B=4, N=2048, C=1024, H=16, HD=64; 8192 token rows.
typedef __bf16 bf16_t;
typedef __attribute__((ext_vector_type(8))) __bf16 bf16x8;
typedef __attribute__((ext_vector_type(4))) __bf16 bf16x4;
typedef __attribute__((ext_vector_type(4))) float floatx4;
typedef __attribute__((ext_vector_type(4))) _Float16 half4_t;

#define GLDS16(g, l)                                                          \
  __builtin_amdgcn_global_load_lds(                                           \
      (const __attribute__((address_space(1))) void*)(g),                     \
      (__attribute__((address_space(3))) void*)(l), 16, 0, 0)

// ---------------------------------------------------------------------------
// C[M,N] = A[M,K] @ B[N,K]^T (+ bias[N]); bf16 in, fp32 acc.
// Tile (32*IT) x (32*JT), BK=64, 4 waves 2x2, ITxJT 16x16 MFMA frags/wave.
// XOR-swizzled GLDS16 staging (round-3: conflicts 0).
// bf16 epilogue: LDS-transposed 16B/lane stores (round-4: WRITE 64MB exact).
// IT/JT picked per GEMM for occupancy: GEMM1 4,4 (2048 blk); GEMM2 4,2
// (1024 blk, 24KB LDS -> 6 resident/CU); Wcomb 2,2 (256 blk).
// ---------------------------------------------------------------------------
template <int IT, int JT, typename OT>
__global__ __launch_bounds__(256) void gemm_bt(
    const bf16_t* __restrict__ A, const bf16_t* __restrict__ B,
    const float* __restrict__ bias, OT* __restrict__ C, int M, int N, int K) {
  constexpr int AROWS = 32 * IT;
  constexpr int BROWS = 32 * JT;
  constexpr int COLS = BROWS;                 // bf16-epilogue tile width
  constexpr int STAGE = (AROWS + BROWS) * 64;
  constexpr int EPI = (sizeof(OT) == 2) ? AROWS * COLS : 0;
  constexpr int SME = STAGE > EPI ? STAGE : EPI;
  __shared__ bf16_t sm[SME];
  bf16_t* As = sm;
  bf16_t* Bs = sm + AROWS * 64;

  const int tid = threadIdx.x;
  const int wave = tid >> 6;
  const int lane = tid & 63;
  const int quad = lane >> 4;
  const int l16 = lane & 15;
  const int m0 = blockIdx.x * AROWS;
  const int n0 = blockIdx.y * BROWS;
  const int wm = (wave >> 1) * (IT * 16);
  const int wn = (wave & 1) * (JT * 16);

  const int ra = wave * (8 * IT) + (lane >> 3);
  const int ga = ((lane & 7) ^ (ra & 7)) * 8;
  const int rb = wave * (8 * JT) + (lane >> 3);
  const int gb = ((lane & 7) ^ (rb & 7)) * 8;
  const bf16_t* Ab = A + (size_t)(m0 + ra) * K + ga;
  const bf16_t* Bb = B + (size_t)(n0 + rb) * K + gb;
  const int p0 = (quad ^ (l16 & 7)) * 8;

  floatx4 acc[IT][JT];
  const floatx4 zf = {0.f, 0.f, 0.f, 0.f};
#pragma unroll
  for (int i = 0; i < IT; ++i)
#pragma unroll
    for (int j = 0; j < JT; ++j) acc[i][j] = zf;

  for (int k0 = 0; k0 < K; k0 += 64) {
#pragma unroll
    for (int t = 0; t < IT; ++t)
      GLDS16(Ab + (size_t)(t * 8) * K + k0, As + (wave * (64 * IT) + t * 64) * 8);
#pragma unroll
    for (int t = 0; t < JT; ++t)
      GLDS16(Bb + (size_t)(t * 8) * K + k0, Bs + (wave * (64 * JT) + t * 64) * 8);
    __syncthreads();
#pragma unroll
    for (int ks = 0; ks < 2; ++ks) {
      const int ko = p0 ^ (ks * 32);
      bf16x8 af[IT], bfr[JT];
#pragma unroll
      for (int i = 0; i < IT; ++i)
        af[i] = *(const bf16x8*)(As + (wm + i * 16 + l16) * 64 + ko);
#pragma unroll
      for (int j = 0; j < JT; ++j)
        bfr[j] = *(const bf16x8*)(Bs + (wn + j * 16 + l16) * 64 + ko);
#pragma unroll
      for (int i = 0; i < IT; ++i)
#pragma unroll
        for (int j = 0; j < JT; ++j)
          acc[i][j] = __builtin_amdgcn_mfma_f32_16x16x32_bf16(
              bfr[j], af[i], acc[i][j], 0, 0, 0);
    }
    __syncthreads();
  }

  if constexpr (sizeof(OT) == 4) {
    // fp32: direct packed stores (64B/row segments)
#pragma unroll
    for (int j = 0; j < JT; ++j) {
      const int colb = n0 + wn + j * 16 + quad * 4;
      floatx4 bv = zf;
      if (bias) bv = *(const floatx4*)(bias + colb);
#pragma unroll
      for (int i = 0; i < IT; ++i) {
        const int row = m0 + wm + i * 16 + l16;
        floatx4 v = acc[i][j] + bv;
        *(floatx4*)((float*)C + (size_t)row * N + colb) = v;
      }
    }
  } else {
    // bf16: LDS round-trip -> 16B/lane coalesced stores. 8B granules,
    // granule swizzle XOR (row&7)*SWZ keeps 16B pairs adjacent (SWZ even).
    constexpr int SWZ = COLS / 32;       // 4 for COLS=128, 2 for COLS=64
    constexpr int CPR = COLS / 8;        // 16B chunks per row
    constexpr int PASSES = (AROWS * CPR) / 256;
#pragma unroll
    for (int j = 0; j < JT; ++j) {
      const int colb = n0 + wn + j * 16 + quad * 4;
      floatx4 bv = zf;
      if (bias) bv = *(const floatx4*)(bias + colb);
      const int gcol = (wn + j * 16 + quad * 4) >> 2;
#pragma unroll
      for (int i = 0; i < IT; ++i) {
        const int rl = wm + i * 16 + l16;
        floatx4 v = acc[i][j] + bv;
        union {
          bf16_t b[4];
          uint2 u2;
        } pk;
        pk.b[0] = (bf16_t)v[0];
        pk.b[1] = (bf16_t)v[1];
        pk.b[2] = (bf16_t)v[2];
        pk.b[3] = (bf16_t)v[3];
        const int gsw = gcol ^ ((rl & 7) * SWZ);
        *(uint2*)(sm + rl * COLS + gsw * 4) = pk.u2;
      }
    }
    __syncthreads();
    bf16_t* Cb = (bf16_t*)C;
#pragma unroll
    for (int pass = 0; pass < PASSES; ++pass) {
      const int f = pass * 256 + tid;
      const int row = f / CPR;
      const int c16 = f % CPR;
      const int g0 = (2 * c16) ^ ((row & 7) * SWZ);
      uint4 v = *(const uint4*)(sm + row * COLS + g0 * 4);
      *(uint4*)(Cb + (size_t)(m0 + row) * N + n0 + c16 * 8) = v;
    }
  }
}

// ---------------------------------------------------------------------------
// prep2: all fp32->bf16 converts, bias assembly, Wcp transpose, bcomb.
// block map: [0,8192) x | [8192,11264) Wqkv | [11264,12288) Wpw |
// [12288,13312) Wout | [13312,14336) Wtw | [14336,14339) bqkv |
// 14339 bias2 | [14340,15364) Wcp transpose | [15364,15620) bcomb
// ---------------------------------------------------------------------------
__global__ __launch_bounds__(256) void prep2_k(
    const float* __restrict__ x, bf16_t* __restrict__ x_bf,
    const float* __restrict__ Wqkv, bf16_t* __restrict__ Wbig1,
    const float* __restrict__ Wpw, bf16_t* __restrict__ Wpw_bf,
    const float* __restrict__ Wout, const float* __restrict__ Wtw,
    bf16_t* __restrict__ Wbig2, const float* __restrict__ bqkv,
    float* __restrict__ bias1, const float* __restrict__ bout,
    const float* __restrict__ btw, float* __restrict__ bias2,
    const float* __restrict__ Wcp, bf16_t* __restrict__ WcpT,
    const float* __restrict__ bcp, const float* __restrict__ bpw) {
  __shared__ float t[32][33];
  const int b = blockIdx.x, tid = threadIdx.x;
  auto cvt4 = [](const float* in, bf16_t* out, int i) {
    floatx4 v = ((const floatx4*)in)[i];
    bf16x4 o;
    o[0] = (bf16_t)v[0];
    o[1] = (bf16_t)v[1];
    o[2] = (bf16_t)v[2];
    o[3] = (bf16_t)v[3];
    ((bf16x4*)out)[i] = o;
  };
  if (b < 8192) {
    cvt4(x, x_bf, b * 256 + tid);
  } else if (b < 11264) {
    cvt4(Wqkv, Wbig1, (b - 8192) * 256 + tid);
  } else if (b < 12288) {
    cvt4(Wpw, Wpw_bf, (b - 11264) * 256 + tid);
  } else if (b < 14336) {
    const bool second = b >= 13312;
    int i = (b - (second ? 13312 : 12288)) * 256 + tid;
    floatx4 v = ((const floatx4*)(second ? Wtw : Wout))[i];
    bf16x4 o;
    o[0] = (bf16_t)v[0];
    o[1] = (bf16_t)v[1];
    o[2] = (bf16_t)v[2];
    o[3] = (bf16_t)v[3];
    int row = i >> 8, c4 = i & 255;
    *(bf16x4*)(Wbig2 + (size_t)row * 2048 + (second ? 1024 : 0) + c4 * 4) = o;
  } else if (b < 14339) {
    int i = (b - 14336) * 256 + tid;
    if (i < 768) ((floatx4*)bias1)[i] = ((const floatx4*)bqkv)[i];
  } else if (b == 14339) {
    ((floatx4*)bias2)[tid] =
        ((const floatx4*)bout)[tid] + ((const floatx4*)btw)[tid];
  } else if (b < 15364) {
    const int tb = b - 14340;
    const int bx = (tb & 31) * 32, by = (tb >> 5) * 32;
    const int tx = tid & 31, ty = tid >> 5;  // 0..7
#pragma unroll
    for (int iq = 0; iq < 4; ++iq)
      t[ty + iq * 8][tx] = Wcp[(size_t)(by + ty + iq * 8) * 1024 + bx + tx];
    __syncthreads();
#pragma unroll
    for (int iq = 0; iq < 4; ++iq)
      WcpT[(size_t)(bx + ty + iq * 8) * 1024 + by + tx] =
          (bf16_t)t[tx][ty + iq * 8];
  } else {
    // bcomb: bias1[3072+row] = Wpw[row,:] . bcp + bpw[row]
    const int row = (b - 15364) * 4 + (tid >> 6);
    const int l = tid & 63;
    const float* wr = Wpw + (size_t)row * 1024;
    float s = 0.f;
    for (int j = l; j < 1024; j += 64) s += wr[j] * bcp[j];
#pragma unroll
    for (int o = 32; o > 0; o >>= 1) s += __shfl_down(s, o);
    if (l == 0) bias1[3072 + row] = s + bpw[row];
  }
}

static __device__ inline void exp8(uint32_t w0, uint32_t w1, uint32_t w2,
                                   uint32_t w3, float* f) {
  f[0] = __uint_as_float(w0 << 16);
  f[1] = __uint_as_float(w0 & 0xffff0000u);
  f[2] = __uint_as_float(w1 << 16);
  f[3] = __uint_as_float(w1 & 0xffff0000u);
  f[4] = __uint_as_float(w2 << 16);
  f[5] = __uint_as_float(w2 & 0xffff0000u);
  f[6] = __uint_as_float(w3 << 16);
  f[7] = __uint_as_float(w3 & 0xffff0000u);
}

// ---------------------------------------------------------------------------
// mid: blocks [0,2048) = MFMA attention (zero LDS, one wave/token);
//      blocks [2048,3072) = depthwise conv k=3.
// ---------------------------------------------------------------------------
__global__ __launch_bounds__(256) void mid_k(const bf16_t* __restrict__ G1,
                                             const float* __restrict__ pos,
                                             const float* __restrict__ Wdw,
                                             const float* __restrict__ bdw,
                                             bf16_t* __restrict__ Mid) {
  const int tid = threadIdx.x;
  if (blockIdx.x < 2048) {
    // ---- attention over heads ----
    const int wave = tid >> 6, lane = tid & 63;
    const int p = blockIdx.x * 4 + wave;
    const int l16 = lane & 15, quad = lane >> 4;
    const bf16_t* row = G1 + (size_t)p * 4096;
    const bf16_t* qb = row + l16 * 192 + quad * 8;

    bf16x8 q0 = *(const bf16x8*)(qb);
    bf16x8 q1 = *(const bf16x8*)(qb + 32);
    bf16x8 k0 = *(const bf16x8*)(qb + 64);
    bf16x8 k1 = *(const bf16x8*)(qb + 96);
    floatx4 S = {0.f, 0.f, 0.f, 0.f};
    S = __builtin_amdgcn_mfma_f32_16x16x32_bf16(k0, q0, S, 0, 0, 0);
    S = __builtin_amdgcn_mfma_f32_16x16x32_bf16(k1, q1, S, 0, 0, 0);

    const floatx4 pb = *(const floatx4*)(pos + (size_t)(p & 2047) * 256 +
                                         l16 * 16 + quad * 4);
    float v[4];
#pragma unroll
    for (int r = 0; r < 4; ++r) v[r] = S[r] * 0.125f + pb[r];

    float m = fmaxf(fmaxf(v[0], v[1]), fmaxf(v[2], v[3]));
    m = fmaxf(m, __shfl_xor(m, 16));
    m = fmaxf(m, __shfl_xor(m, 32));
    float e[4], sum = 0.f;
#pragma unroll
    for (int r = 0; r < 4; ++r) {
      e[r] = __expf(v[r] - m);
      sum += e[r];
    }
    sum += __shfl_xor(sum, 16);
    sum += __shfl_xor(sum, 32);
    const float inv = 1.0f / sum;
    half4_t pa;
#pragma unroll
    for (int r = 0; r < 4; ++r) pa[r] = (_Float16)(e[r] * inv);

    const bf16_t* vb_base = row + 128 + l16;
    const floatx4 zf = {0.f, 0.f, 0.f, 0.f};
    floatx4 o[4];
#pragma unroll
    for (int t = 0; t < 4; ++t) {
      half4_t vb;
#pragma unroll
      for (int j = 0; j < 4; ++j)
        vb[j] = (_Float16)(float)vb_base[(quad * 4 + j) * 192 + t * 16];
      o[t] = __builtin_amdgcn_mfma_f32_16x16x16f16(pa, vb, zf, 0, 0, 0);
    }

    bf16_t* ob = Mid + (size_t)p * 2048 + (quad * 4) * 64 + l16;
#pragma unroll
    for (int r = 0; r < 4; ++r)
#pragma unroll
      for (int t = 0; t < 4; ++t) ob[r * 64 + t * 16] = (bf16_t)o[t][r];
  } else {
    // ---- depthwise conv ----
    const bf16_t* in = G1 + 3072;       // row-stride 4096
    bf16_t* out = Mid + 1024;           // row-stride 2048
    const int item = (blockIdx.x - 2048) * 256 + tid;  // 262144
    const int cc = item & 127, rowg = item >> 7;
    const int c0 = cc * 8;
    float w0[8], w1[8], w2[8], bb[8];
#pragma unroll
    for (int c = 0; c < 8; ++c) {
      w0[c] = Wdw[(c0 + c) * 3];
      w1[c] = Wdw[(c0 + c) * 3 + 1];
      w2[c] = Wdw[(c0 + c) * 3 + 2];
      bb[c] = bdw[c0 + c];
    }
#pragma unroll
    for (int jr = 0; jr < 4; ++jr) {
      const int tt = rowg * 4 + jr;
      const int n = tt & 2047;
      const bf16_t* ip = in + (size_t)tt * 4096 + c0;
      const uint4 z4 = {0, 0, 0, 0};
      uint4 um = (n > 0) ? *(const uint4*)(ip - 4096) : z4;
      uint4 uc = *(const uint4*)(ip);
      uint4 up = (n < 2047) ? *(const uint4*)(ip + 4096) : z4;
      float fm[8], fc[8], fp[8];
      exp8(um.x, um.y, um.z, um.w, fm);
      exp8(uc.x, uc.y, uc.z, uc.w, fc);
      exp8(up.x, up.y, up.z, up.w, fp);
      union {
        bf16_t b[8];
        uint4 u;
      } pk;
#pragma unroll
      for (int c = 0; c < 8; ++c)
        pk.b[c] =
            (bf16_t)(bb[c] + fm[c] * w0[c] + fc[c] * w1[c] + fp[c] * w2[c]);
      *(uint4*)(out + (size_t)tt * 2048 + c0) = pk.u;
    }
  }
}

// ---------------------------------------------------------------------------
extern "C" void kernel_launch(void* const* d_in, const int* in_sizes, int n_in,
                              void* d_out, int out_size, void* d_ws,
                              size_t ws_size, hipStream_t stream) {
  (void)in_sizes; (void)n_in; (void)out_size; (void)ws_size;
  const float* x = (const float*)d_in[0];
  const float* Wqkv = (const float*)d_in[1];
  const float* bqkv = (const float*)d_in[2];
  const float* Wout = (const float*)d_in[3];
  const float* bout = (const float*)d_in[4];
  const float* pos = (const float*)d_in[5];
  const float* Wcp = (const float*)d_in[6];
  const float* bcp = (const float*)d_in[7];
  const float* Wpw = (const float*)d_in[8];
  const float* bpw = (const float*)d_in[9];
  const float* Wdw = (const float*)d_in[10];
  const float* bdw = (const float*)d_in[11];
  const float* Wtw = (const float*)d_in[12];
  const float* btw = (const float*)d_in[13];
  float* out = (float*)d_out;

  char* ws = (char*)d_ws;
  const size_t MB = 1024ull * 1024ull;
  bf16_t* x_bf = (bf16_t*)(ws + 0);              // 16 MB (dead after GEMM1)
  bf16_t* Wbig1 = (bf16_t*)(ws + 16 * MB);       // 8 MB: [Wqkv ; Wcomb]
  bf16_t* WcpT = (bf16_t*)(ws + 24 * MB);        // 2 MB
  bf16_t* Wpw_bf = (bf16_t*)(ws + 26 * MB);      // 2 MB
  bf16_t* Mid = (bf16_t*)(ws + 0);               // 32 MB (after GEMM1)
  bf16_t* Wbig2 = (bf16_t*)(ws + 32 * MB);       // 4 MB: [Wout|Wtw] K-concat
  float* bias1 = (float*)(ws + 36 * MB);         // 16 KB
  float* bias2 = (float*)(ws + 36 * MB + 65536); // 4 KB
  bf16_t* G1out = (bf16_t*)(ws + 37 * MB);       // 64 MB: 8192 x 4096

  prep2_k<<<15620, 256, 0, stream>>>(x, x_bf, Wqkv, Wbig1, Wpw, Wpw_bf, Wout,
                                     Wtw, Wbig2, bqkv, bias1, bout, btw, bias2,
                                     Wcp, WcpT, bcp, bpw);

  // W_comb = W_pw @ W_cp -> rows 3072..4095 of Wbig1 (64x64 tiles, 256 blk)
  gemm_bt<2, 2, bf16_t><<<dim3(16, 16), 256, 0, stream>>>(
      Wpw_bf, WcpT, nullptr, Wbig1 + (size_t)3072 * 1024, 1024, 1024, 1024);

  // GEMM1: x @ [Wqkv ; Wcomb]^T + [bqkv ; bcomb] -> 8192 x 4096
  gemm_bt<4, 4, bf16_t><<<dim3(64, 32), 256, 0, stream>>>(
      x_bf, Wbig1, bias1, G1out, 8192, 4096, 1024);

  // attention (cols 0..3071) -> Mid cols 0..1023; dwconv -> Mid cols 1024..
  mid_k<<<3072, 256, 0, stream>>>(G1out, pos, Wdw, bdw, Mid);

  // GEMM2: [attn|dwc] @ [Wout|Wtw]^T + (bout+btw) -> out (128x64 tiles)
  gemm_bt<4, 2, float><<<dim3(64, 16), 256, 0, stream>>>(Mid, Wbig2, bias2,
                                                         out, 8192, 1024, 2048);
}

// Round 6
// 278.284 us; speedup vs baseline: 1.3393x; 1.0023x over previous
//
#include <hip/hip_runtime.h>
#include <hip/hip_bf16.h>
#include <stdint.h>

// B=4, N=2048, C=1024, H=16, HD=64; 8192 token rows.
typedef __bf16 bf16_t;
typedef __attribute__((ext_vector_type(8))) __bf16 bf16x8;
typedef __attribute__((ext_vector_type(4))) __bf16 bf16x4;
typedef __attribute__((ext_vector_type(4))) float floatx4;
typedef __attribute__((ext_vector_type(4))) _Float16 half4_t;

#define GLDS16(g, l)                                                          \
  __builtin_amdgcn_global_load_lds(                                           \
      (const __attribute__((address_space(1))) void*)(g),                     \
      (__attribute__((address_space(3))) void*)(l), 16, 0, 0)

// ---------------------------------------------------------------------------
// C[M,N] = A[M,K] @ B[N,K]^T (+ bias[N]); bf16 in, fp32 acc.
// Tile (32*IT) x (32*JT), BK=64, 4 waves 2x2, ITxJT 16x16 MFMA frags/wave.
// XOR-swizzled GLDS16 staging (round-3: conflicts 0).
// bf16 epilogue: LDS-transposed 16B/lane stores (round-4: WRITE 64MB exact).
// Tiles: GEMM1 4,4 (2048 blk); GEMM2 4,4 grid 512 (2/CU — GEMM1-plateau
// staging ratio beats round-5's 128x64 higher-occupancy variant);
// Wcomb 2,2 (256 blk).
// ---------------------------------------------------------------------------
template <int IT, int JT, typename OT>
__global__ __launch_bounds__(256) void gemm_bt(
    const bf16_t* __restrict__ A, const bf16_t* __restrict__ B,
    const float* __restrict__ bias, OT* __restrict__ C, int M, int N, int K) {
  constexpr int AROWS = 32 * IT;
  constexpr int BROWS = 32 * JT;
  constexpr int COLS = BROWS;
  constexpr int STAGE = (AROWS + BROWS) * 64;
  constexpr int EPI = (sizeof(OT) == 2) ? AROWS * COLS : 0;
  constexpr int SME = STAGE > EPI ? STAGE : EPI;
  __shared__ bf16_t sm[SME];
  bf16_t* As = sm;
  bf16_t* Bs = sm + AROWS * 64;

  const int tid = threadIdx.x;
  const int wave = tid >> 6;
  const int lane = tid & 63;
  const int quad = lane >> 4;
  const int l16 = lane & 15;
  const int m0 = blockIdx.x * AROWS;
  const int n0 = blockIdx.y * BROWS;
  const int wm = (wave >> 1) * (IT * 16);
  const int wn = (wave & 1) * (JT * 16);

  const int ra = wave * (8 * IT) + (lane >> 3);
  const int ga = ((lane & 7) ^ (ra & 7)) * 8;
  const int rb = wave * (8 * JT) + (lane >> 3);
  const int gb = ((lane & 7) ^ (rb & 7)) * 8;
  const bf16_t* Ab = A + (size_t)(m0 + ra) * K + ga;
  const bf16_t* Bb = B + (size_t)(n0 + rb) * K + gb;
  const int p0 = (quad ^ (l16 & 7)) * 8;

  floatx4 acc[IT][JT];
  const floatx4 zf = {0.f, 0.f, 0.f, 0.f};
#pragma unroll
  for (int i = 0; i < IT; ++i)
#pragma unroll
    for (int j = 0; j < JT; ++j) acc[i][j] = zf;

  for (int k0 = 0; k0 < K; k0 += 64) {
#pragma unroll
    for (int t = 0; t < IT; ++t)
      GLDS16(Ab + (size_t)(t * 8) * K + k0, As + (wave * (64 * IT) + t * 64) * 8);
#pragma unroll
    for (int t = 0; t < JT; ++t)
      GLDS16(Bb + (size_t)(t * 8) * K + k0, Bs + (wave * (64 * JT) + t * 64) * 8);
    __syncthreads();
#pragma unroll
    for (int ks = 0; ks < 2; ++ks) {
      const int ko = p0 ^ (ks * 32);
      bf16x8 af[IT], bfr[JT];
#pragma unroll
      for (int i = 0; i < IT; ++i)
        af[i] = *(const bf16x8*)(As + (wm + i * 16 + l16) * 64 + ko);
#pragma unroll
      for (int j = 0; j < JT; ++j)
        bfr[j] = *(const bf16x8*)(Bs + (wn + j * 16 + l16) * 64 + ko);
#pragma unroll
      for (int i = 0; i < IT; ++i)
#pragma unroll
        for (int j = 0; j < JT; ++j)
          acc[i][j] = __builtin_amdgcn_mfma_f32_16x16x32_bf16(
              bfr[j], af[i], acc[i][j], 0, 0, 0);
    }
    __syncthreads();
  }

  if constexpr (sizeof(OT) == 4) {
#pragma unroll
    for (int j = 0; j < JT; ++j) {
      const int colb = n0 + wn + j * 16 + quad * 4;
      floatx4 bv = zf;
      if (bias) bv = *(const floatx4*)(bias + colb);
#pragma unroll
      for (int i = 0; i < IT; ++i) {
        const int row = m0 + wm + i * 16 + l16;
        floatx4 v = acc[i][j] + bv;
        *(floatx4*)((float*)C + (size_t)row * N + colb) = v;
      }
    }
  } else {
    constexpr int SWZ = COLS / 32;
    constexpr int CPR = COLS / 8;
    constexpr int PASSES = (AROWS * CPR) / 256;
#pragma unroll
    for (int j = 0; j < JT; ++j) {
      const int colb = n0 + wn + j * 16 + quad * 4;
      floatx4 bv = zf;
      if (bias) bv = *(const floatx4*)(bias + colb);
      const int gcol = (wn + j * 16 + quad * 4) >> 2;
#pragma unroll
      for (int i = 0; i < IT; ++i) {
        const int rl = wm + i * 16 + l16;
        floatx4 v = acc[i][j] + bv;
        union {
          bf16_t b[4];
          uint2 u2;
        } pk;
        pk.b[0] = (bf16_t)v[0];
        pk.b[1] = (bf16_t)v[1];
        pk.b[2] = (bf16_t)v[2];
        pk.b[3] = (bf16_t)v[3];
        const int gsw = gcol ^ ((rl & 7) * SWZ);
        *(uint2*)(sm + rl * COLS + gsw * 4) = pk.u2;
      }
    }
    __syncthreads();
    bf16_t* Cb = (bf16_t*)C;
#pragma unroll
    for (int pass = 0; pass < PASSES; ++pass) {
      const int f = pass * 256 + tid;
      const int row = f / CPR;
      const int c16 = f % CPR;
      const int g0 = (2 * c16) ^ ((row & 7) * SWZ);
      uint4 v = *(const uint4*)(sm + row * COLS + g0 * 4);
      *(uint4*)(Cb + (size_t)(m0 + row) * N + n0 + c16 * 8) = v;
    }
  }
}

// ---------------------------------------------------------------------------
// prep2: all fp32->bf16 converts, bias assembly, Wcp transpose, bcomb.
// ---------------------------------------------------------------------------
__global__ __launch_bounds__(256) void prep2_k(
    const float* __restrict__ x, bf16_t* __restrict__ x_bf,
    const float* __restrict__ Wqkv, bf16_t* __restrict__ Wbig1,
    const float* __restrict__ Wpw, bf16_t* __restrict__ Wpw_bf,
    const float* __restrict__ Wout, const float* __restrict__ Wtw,
    bf16_t* __restrict__ Wbig2, const float* __restrict__ bqkv,
    float* __restrict__ bias1, const float* __restrict__ bout,
    const float* __restrict__ btw, float* __restrict__ bias2,
    const float* __restrict__ Wcp, bf16_t* __restrict__ WcpT,
    const float* __restrict__ bcp, const float* __restrict__ bpw) {
  __shared__ float t[32][33];
  const int b = blockIdx.x, tid = threadIdx.x;
  auto cvt4 = [](const float* in, bf16_t* out, int i) {
    floatx4 v = ((const floatx4*)in)[i];
    bf16x4 o;
    o[0] = (bf16_t)v[0];
    o[1] = (bf16_t)v[1];
    o[2] = (bf16_t)v[2];
    o[3] = (bf16_t)v[3];
    ((bf16x4*)out)[i] = o;
  };
  if (b < 8192) {
    cvt4(x, x_bf, b * 256 + tid);
  } else if (b < 11264) {
    cvt4(Wqkv, Wbig1, (b - 8192) * 256 + tid);
  } else if (b < 12288) {
    cvt4(Wpw, Wpw_bf, (b - 11264) * 256 + tid);
  } else if (b < 14336) {
    const bool second = b >= 13312;
    int i = (b - (second ? 13312 : 12288)) * 256 + tid;
    floatx4 v = ((const floatx4*)(second ? Wtw : Wout))[i];
    bf16x4 o;
    o[0] = (bf16_t)v[0];
    o[1] = (bf16_t)v[1];
    o[2] = (bf16_t)v[2];
    o[3] = (bf16_t)v[3];
    int row = i >> 8, c4 = i & 255;
    *(bf16x4*)(Wbig2 + (size_t)row * 2048 + (second ? 1024 : 0) + c4 * 4) = o;
  } else if (b < 14339) {
    int i = (b - 14336) * 256 + tid;
    if (i < 768) ((floatx4*)bias1)[i] = ((const floatx4*)bqkv)[i];
  } else if (b == 14339) {
    ((floatx4*)bias2)[tid] =
        ((const floatx4*)bout)[tid] + ((const floatx4*)btw)[tid];
  } else if (b < 15364) {
    const int tb = b - 14340;
    const int bx = (tb & 31) * 32, by = (tb >> 5) * 32;
    const int tx = tid & 31, ty = tid >> 5;
#pragma unroll
    for (int iq = 0; iq < 4; ++iq)
      t[ty + iq * 8][tx] = Wcp[(size_t)(by + ty + iq * 8) * 1024 + bx + tx];
    __syncthreads();
#pragma unroll
    for (int iq = 0; iq < 4; ++iq)
      WcpT[(size_t)(bx + ty + iq * 8) * 1024 + by + tx] =
          (bf16_t)t[tx][ty + iq * 8];
  } else {
    const int row = (b - 15364) * 4 + (tid >> 6);
    const int l = tid & 63;
    const float* wr = Wpw + (size_t)row * 1024;
    float s = 0.f;
    for (int j = l; j < 1024; j += 64) s += wr[j] * bcp[j];
#pragma unroll
    for (int o = 32; o > 0; o >>= 1) s += __shfl_down(s, o);
    if (l == 0) bias1[3072 + row] = s + bpw[row];
  }
}

static __device__ inline void exp8(uint32_t w0, uint32_t w1, uint32_t w2,
                                   uint32_t w3, float* f) {
  f[0] = __uint_as_float(w0 << 16);
  f[1] = __uint_as_float(w0 & 0xffff0000u);
  f[2] = __uint_as_float(w1 << 16);
  f[3] = __uint_as_float(w1 & 0xffff0000u);
  f[4] = __uint_as_float(w2 << 16);
  f[5] = __uint_as_float(w2 & 0xffff0000u);
  f[6] = __uint_as_float(w3 << 16);
  f[7] = __uint_as_float(w3 & 0xffff0000u);
}

// ---------------------------------------------------------------------------
// mid: blocks [0,2048) = MFMA attention (one wave/token);
//      blocks [2048,3072) = depthwise conv k=3.
// Attention output re-packed through per-wave LDS (stride-68 rows: write
// banks spread, read-back 2-way = free) -> 2 coalesced uint4 stores/lane
// (fixes 32B-segment RMW write amplification on the 16MB attn output).
// ---------------------------------------------------------------------------
__global__ __launch_bounds__(256) void mid_k(const bf16_t* __restrict__ G1,
                                             const float* __restrict__ pos,
                                             const float* __restrict__ Wdw,
                                             const float* __restrict__ bdw,
                                             bf16_t* __restrict__ Mid) {
  __shared__ bf16_t ost[4][16 * 68];
  const int tid = threadIdx.x;
  if (blockIdx.x < 2048) {
    const int wave = tid >> 6, lane = tid & 63;
    const int p = blockIdx.x * 4 + wave;
    const int l16 = lane & 15, quad = lane >> 4;
    const bf16_t* row = G1 + (size_t)p * 4096;
    const bf16_t* qb = row + l16 * 192 + quad * 8;

    bf16x8 q0 = *(const bf16x8*)(qb);
    bf16x8 q1 = *(const bf16x8*)(qb + 32);
    bf16x8 k0 = *(const bf16x8*)(qb + 64);
    bf16x8 k1 = *(const bf16x8*)(qb + 96);
    floatx4 S = {0.f, 0.f, 0.f, 0.f};
    S = __builtin_amdgcn_mfma_f32_16x16x32_bf16(k0, q0, S, 0, 0, 0);
    S = __builtin_amdgcn_mfma_f32_16x16x32_bf16(k1, q1, S, 0, 0, 0);

    const floatx4 pb = *(const floatx4*)(pos + (size_t)(p & 2047) * 256 +
                                         l16 * 16 + quad * 4);
    float v[4];
#pragma unroll
    for (int r = 0; r < 4; ++r) v[r] = S[r] * 0.125f + pb[r];

    float m = fmaxf(fmaxf(v[0], v[1]), fmaxf(v[2], v[3]));
    m = fmaxf(m, __shfl_xor(m, 16));
    m = fmaxf(m, __shfl_xor(m, 32));
    float e[4], sum = 0.f;
#pragma unroll
    for (int r = 0; r < 4; ++r) {
      e[r] = __expf(v[r] - m);
      sum += e[r];
    }
    sum += __shfl_xor(sum, 16);
    sum += __shfl_xor(sum, 32);
    const float inv = 1.0f / sum;
    half4_t pa;
#pragma unroll
    for (int r = 0; r < 4; ++r) pa[r] = (_Float16)(e[r] * inv);

    const bf16_t* vb_base = row + 128 + l16;
    const floatx4 zf = {0.f, 0.f, 0.f, 0.f};
    floatx4 o[4];
#pragma unroll
    for (int t = 0; t < 4; ++t) {
      half4_t vb;
#pragma unroll
      for (int j = 0; j < 4; ++j)
        vb[j] = (_Float16)(float)vb_base[(quad * 4 + j) * 192 + t * 16];
      o[t] = __builtin_amdgcn_mfma_f32_16x16x16f16(pa, vb, zf, 0, 0, 0);
    }

    // stage O[h][d] -> LDS rows of 68, then coalesced read-back
    bf16_t* ow = ost[wave];
#pragma unroll
    for (int r = 0; r < 4; ++r)
#pragma unroll
      for (int t = 0; t < 4; ++t)
        ow[(quad * 4 + r) * 68 + t * 16 + l16] = (bf16_t)o[t][r];
    // same-wave LDS: compiler inserts lgkmcnt waits (aliasing pointer)
    const int h2 = lane >> 2, m4 = lane & 3;
    const bf16_t* srcp = ow + h2 * 68 + m4 * 16;
    uint2 a0 = *(const uint2*)(srcp);
    uint2 a1 = *(const uint2*)(srcp + 4);
    uint2 a2 = *(const uint2*)(srcp + 8);
    uint2 a3 = *(const uint2*)(srcp + 12);
    uint4 s0 = {a0.x, a0.y, a1.x, a1.y};
    uint4 s1 = {a2.x, a2.y, a3.x, a3.y};
    uint4* dst = (uint4*)(Mid + (size_t)p * 2048 + h2 * 64 + m4 * 16);
    dst[0] = s0;
    dst[1] = s1;
  } else {
    const bf16_t* in = G1 + 3072;
    bf16_t* out = Mid + 1024;
    const int item = (blockIdx.x - 2048) * 256 + tid;
    const int cc = item & 127, rowg = item >> 7;
    const int c0 = cc * 8;
    float w0[8], w1[8], w2[8], bb[8];
#pragma unroll
    for (int c = 0; c < 8; ++c) {
      w0[c] = Wdw[(c0 + c) * 3];
      w1[c] = Wdw[(c0 + c) * 3 + 1];
      w2[c] = Wdw[(c0 + c) * 3 + 2];
      bb[c] = bdw[c0 + c];
    }
#pragma unroll
    for (int jr = 0; jr < 4; ++jr) {
      const int tt = rowg * 4 + jr;
      const int n = tt & 2047;
      const bf16_t* ip = in + (size_t)tt * 4096 + c0;
      const uint4 z4 = {0, 0, 0, 0};
      uint4 um = (n > 0) ? *(const uint4*)(ip - 4096) : z4;
      uint4 uc = *(const uint4*)(ip);
      uint4 up = (n < 2047) ? *(const uint4*)(ip + 4096) : z4;
      float fm[8], fc[8], fp[8];
      exp8(um.x, um.y, um.z, um.w, fm);
      exp8(uc.x, uc.y, uc.z, uc.w, fc);
      exp8(up.x, up.y, up.z, up.w, fp);
      union {
        bf16_t b[8];
        uint4 u;
      } pk;
#pragma unroll
      for (int c = 0; c < 8; ++c)
        pk.b[c] =
            (bf16_t)(bb[c] + fm[c] * w0[c] + fc[c] * w1[c] + fp[c] * w2[c]);
      *(uint4*)(out + (size_t)tt * 2048 + c0) = pk.u;
    }
  }
}

// ---------------------------------------------------------------------------
extern "C" void kernel_launch(void* const* d_in, const int* in_sizes, int n_in,
                              void* d_out, int out_size, void* d_ws,
                              size_t ws_size, hipStream_t stream) {
  (void)in_sizes; (void)n_in; (void)out_size; (void)ws_size;
  const float* x = (const float*)d_in[0];
  const float* Wqkv = (const float*)d_in[1];
  const float* bqkv = (const float*)d_in[2];
  const float* Wout = (const float*)d_in[3];
  const float* bout = (const float*)d_in[4];
  const float* pos = (const float*)d_in[5];
  const float* Wcp = (const float*)d_in[6];
  const float* bcp = (const float*)d_in[7];
  const float* Wpw = (const float*)d_in[8];
  const float* bpw = (const float*)d_in[9];
  const float* Wdw = (const float*)d_in[10];
  const float* bdw = (const float*)d_in[11];
  const float* Wtw = (const float*)d_in[12];
  const float* btw = (const float*)d_in[13];
  float* out = (float*)d_out;

  char* ws = (char*)d_ws;
  const size_t MB = 1024ull * 1024ull;
  bf16_t* x_bf = (bf16_t*)(ws + 0);              // 16 MB (dead after GEMM1)
  bf16_t* Wbig1 = (bf16_t*)(ws + 16 * MB);       // 8 MB: [Wqkv ; Wcomb]
  bf16_t* WcpT = (bf16_t*)(ws + 24 * MB);        // 2 MB
  bf16_t* Wpw_bf = (bf16_t*)(ws + 26 * MB);      // 2 MB
  bf16_t* Mid = (bf16_t*)(ws + 0);               // 32 MB (after GEMM1)
  bf16_t* Wbig2 = (bf16_t*)(ws + 32 * MB);       // 4 MB: [Wout|Wtw] K-concat
  float* bias1 = (float*)(ws + 36 * MB);         // 16 KB
  float* bias2 = (float*)(ws + 36 * MB + 65536); // 4 KB
  bf16_t* G1out = (bf16_t*)(ws + 37 * MB);       // 64 MB: 8192 x 4096

  prep2_k<<<15620, 256, 0, stream>>>(x, x_bf, Wqkv, Wbig1, Wpw, Wpw_bf, Wout,
                                     Wtw, Wbig2, bqkv, bias1, bout, btw, bias2,
                                     Wcp, WcpT, bcp, bpw);

  // W_comb = W_pw @ W_cp -> rows 3072..4095 of Wbig1
  gemm_bt<2, 2, bf16_t><<<dim3(16, 16), 256, 0, stream>>>(
      Wpw_bf, WcpT, nullptr, Wbig1 + (size_t)3072 * 1024, 1024, 1024, 1024);

  // GEMM1: x @ [Wqkv ; Wcomb]^T + [bqkv ; bcomb] -> 8192 x 4096
  gemm_bt<4, 4, bf16_t><<<dim3(64, 32), 256, 0, stream>>>(
      x_bf, Wbig1, bias1, G1out, 8192, 4096, 1024);

  // attention (cols 0..3071) -> Mid cols 0..1023; dwconv -> Mid cols 1024..
  mid_k<<<3072, 256, 0, stream>>>(G1out, pos, Wdw, bdw, Mid);

  // GEMM2: [attn|dwc] @ [Wout|Wtw]^T + (bout+btw) -> out (128x128 tiles)
  gemm_bt<4, 4, float><<<dim3(64, 8), 256, 0, stream>>>(Mid, Wbig2, bias2,
                                                        out, 8192, 1024, 2048);
}